// Round 2
// baseline (868.620 us; speedup 1.0000x reference)
//
#include <hip/hip_runtime.h>
#include <cstdint>

#define EPSF 1e-5f

namespace {

typedef _Float16 f16;
typedef _Float16 v8h __attribute__((ext_vector_type(8)));
typedef float v4f __attribute__((ext_vector_type(4)));

constexpr int B  = 32;
constexpr int T0 = 2048, F0 = 20;
constexpr int T1 = 2044, T2 = 2040, T3 = 2034;
constexpr int TS = 2048;   // uniform stored t-rows per (b, channel-octet)

// async global->LDS DMA, 16B per lane; LDS dest = wave-uniform base + lane*16
__device__ __forceinline__ void gload16(const void* g, void* l) {
    typedef const __attribute__((address_space(1))) void* gp_t;
    typedef __attribute__((address_space(3))) void* lp_t;
    __builtin_amdgcn_global_load_lds((gp_t)(unsigned long long)g,
                                     (lp_t)(unsigned int)(unsigned long long)l,
                                     16, 0, 0);
}
__device__ __forceinline__ void wait_vm8() { asm volatile("s_waitcnt vmcnt(8)" ::: "memory"); }
__device__ __forceinline__ void wait_vm4() { asm volatile("s_waitcnt vmcnt(4)" ::: "memory"); }
__device__ __forceinline__ void wait_vm0() { asm volatile("s_waitcnt vmcnt(0)" ::: "memory"); }

#define BARRIER asm volatile("s_barrier" ::: "memory")

// x [B, T0, F0] fp32 -> xT [b][3 oct][TS][8] fp16; first blocks also zero st[4096]
__global__ __launch_bounds__(256) void transpose_x(const float* __restrict__ x,
                                                   f16* __restrict__ xT,
                                                   float* __restrict__ stZ)
{
    int idx = blockIdx.x * 256 + threadIdx.x;
    if (idx < 4096) stZ[idx] = 0.f;            // zero st1..st4 (atomic stats targets)
    constexpr int total = B * 3 * TS * 8;
    if (idx >= total) return;
    int fl = idx & 7;
    int t  = (idx >> 3) & (TS - 1);
    int fo = (idx >> 14) % 3;
    int b  = idx / (3 << 14);
    int f  = fo * 8 + fl;
    float v = (f < F0) ? x[((size_t)b * T0 + t) * F0 + f] : 0.f;
    xT[idx] = (f16)v;
}

// Fold prev-layer BN into weights, cast fp16, reorder K c-major (k = c*FP + f),
// write SWIZZLED slab order [o/128][k/8][o%128][8]. FP,C compile-time -> no v_rcp divs.
template<int FP, int C>
__global__ __launch_bounds__(256) void fold_mfma(
    const float* __restrict__ W, const float* __restrict__ bias,
    const float* __restrict__ st, const float* __restrict__ gamma, const float* __restrict__ beta,
    f16* __restrict__ Wh, float* __restrict__ bf,
    int Oreal, int Freal, int Cin, int CinOrig, float invN)
{
    int o = blockIdx.x;
    auto sidx = [&](int k) {
        return ((size_t)((o >> 7) * (Cin >> 3) + (k >> 3)) * 128 + (o & 127)) * 8 + (k & 7);
    };
    if (o >= Oreal) {
        for (int k = threadIdx.x; k < Cin; k += 256) Wh[sidx(k)] = (f16)0.f;
        if (threadIdx.x == 0) bf[o] = 0.f;
        return;
    }
    float local = 0.f;
    for (int k = threadIdx.x; k < Cin; k += 256) {
        int c = k / FP, f = k - c * FP;        // FP constexpr -> magic-mul/shift
        float wv = 0.f;
        if (c < C && f < Freal) {
            float sc = 1.f, sh = 0.f;
            if (st) {
                float mean = st[f] * invN;
                float var  = st[Freal + f] * invN - mean * mean;
                sc = rsqrtf(var + EPSF);
                if (gamma) sc *= gamma[f];
                sh = (beta ? beta[f] : 0.f) - mean * sc;
            }
            float w = W[(size_t)o * CinOrig + f * C + c];
            wv = w * sc;
            local += w * sh;
        }
        Wh[sidx(k)] = (f16)wv;
    }
#pragma unroll
    for (int d = 32; d; d >>= 1) local += __shfl_down(local, d);
    __shared__ float red[4];
    if ((threadIdx.x & 63) == 0) red[threadIdx.x >> 6] = local;
    __syncthreads();
    if (threadIdx.x == 0) bf[o] = bias[o] + red[0] + red[1] + red[2] + red[3];
}

// L1 only (CIN=128): fused splice+conv via MFMA, 128x128 tile, 2-phase pipeline.
template<int ACT, int FPR, int CIN>
__global__ __launch_bounds__(256, 4) void conv_mfma(
    const f16* __restrict__ inT, const f16* __restrict__ Wh,
    const float* __restrict__ bias, f16* __restrict__ outT,
    float* __restrict__ st, int O, int Tout, int offMul)
{
    __shared__ __align__(16) f16 Ilds[2][4 * 128 * 8];
    __shared__ __align__(16) f16 Wlds[2][4 * 128 * 8];
    __shared__ float redS[2][128];
    __shared__ float redQ[2][128];
    const int tid  = threadIdx.x;
    const int lane = tid & 63, wave = tid >> 6;
    const int wt = wave & 1, wo = wave >> 1;
    const int quad = lane >> 4, l16 = lane & 15;
    const int tB = blockIdx.x * 128, oB = blockIdx.y * 128, b = blockIdx.z;
    const f16* inb = inT + (size_t)b * FPR * TS;
    const size_t wBase = (size_t)(oB >> 7) * (CIN >> 3);

    v4f acc[4][4];
#pragma unroll
    for (int mi = 0; mi < 4; ++mi)
#pragma unroll
        for (int ni = 0; ni < 4; ++ni)
#pragma unroll
            for (int r = 0; r < 4; ++r) acc[mi][ni][r] = 0.f;

    constexpr int nIter = CIN >> 5;

    auto compute = [&](int pb) {
        v8h afr[4], bfr[4];
#pragma unroll
        for (int mi = 0; mi < 4; ++mi)
            afr[mi] = *(const v8h*)&Ilds[pb][(quad * 128 + wt * 64 + mi * 16 + l16) * 8];
#pragma unroll
        for (int ni = 0; ni < 4; ++ni)
            bfr[ni] = *(const v8h*)&Wlds[pb][(quad * 128 + wo * 64 + ni * 16 + l16) * 8];
#pragma unroll
        for (int mi = 0; mi < 4; ++mi)
#pragma unroll
            for (int ni = 0; ni < 4; ++ni)
                acc[mi][ni] = __builtin_amdgcn_mfma_f32_16x16x32_f16(
                    afr[mi], bfr[ni], acc[mi][ni], 0, 0, 0);
    };

    auto stage = [&](int iB, int pb) {
#pragma unroll
        for (int j = 0; j < 4; ++j) {
            int s = wave * 4 + j;
            int koct = (s & 7) >> 1, half = s & 1;
            if (s < 8) {
                int kidx = iB + koct * 8;
                int c = kidx / FPR, f = kidx - c * FPR;
                int t = tB + half * 64 + lane + c * offMul;
                gload16(inb + ((size_t)(f >> 3) * TS + t) * 8,
                        &Ilds[pb][(koct * 128 + half * 64) * 8]);
            } else {
                gload16(Wh + ((wBase + (iB >> 3) + koct) * 128 + half * 64 + lane) * 8,
                        &Wlds[pb][(koct * 128 + half * 64) * 8]);
            }
        }
    };
    stage(0, 0);
#pragma unroll 2
    for (int k = 0; k < nIter; ++k) {
        const int pb = k & 1;
        __syncthreads();
        if (k + 1 < nIter) { stage((k + 1) * 32, pb ^ 1); wait_vm4(); }
        else               { wait_vm0(); }
        __syncthreads();
        compute(pb);
    }

    float Sl[4] = {0, 0, 0, 0}, Ql[4] = {0, 0, 0, 0};
#pragma unroll
    for (int ni = 0; ni < 4; ++ni) {
        const int o  = oB + wo * 64 + ni * 16 + l16;
        const float bs = bias[o];
        f16* orow = outT + (size_t)b * O * TS + (size_t)(o >> 3) * TS * 8 + (o & 7);
#pragma unroll
        for (int mi = 0; mi < 4; ++mi)
#pragma unroll
            for (int r = 0; r < 4; ++r) {
                int t = tB + wt * 64 + mi * 16 + quad * 4 + r;
                if (t < Tout) {
                    float v = acc[mi][ni][r] + bs;
                    v = fmaxf(v, 0.f);
                    if (ACT == 2) v = fminf(v, 6.f);
                    orow[(size_t)t * 8] = (f16)v;
                    Sl[ni] += v; Ql[ni] += v * v;
                }
            }
    }
#pragma unroll
    for (int ni = 0; ni < 4; ++ni) {
        float s = Sl[ni], q = Ql[ni];
        s += __shfl_down(s, 32); q += __shfl_down(q, 32);
        s += __shfl_down(s, 16); q += __shfl_down(q, 16);
        if (lane < 16) {
            redS[wt][wo * 64 + ni * 16 + lane] = s;
            redQ[wt][wo * 64 + ni * 16 + lane] = q;
        }
    }
    __syncthreads();
    if (tid < 128) {
        atomicAdd(&st[oB + tid],       redS[0][tid] + redS[1][tid]);
        atomicAdd(&st[512 + oB + tid], redQ[0][tid] + redQ[1][tid]);
    }
}

// ---------------------------------------------------------------------------
// 256x256-tile 8-wave 8-phase MFMA conv with ONE-PHASE REGISTER READ-AHEAD:
// ds_reads issued in phase p fill fragment regs for phase p+1's MFMA; counted
// lgkmcnt(N) (DS retires in order) keeps the just-issued reads in flight under
// the current MFMA cluster -> LDS-read time (~4.6k cy/iter) hides under MFMA
// (~5.0k cy/iter) instead of serializing (R1 post-mortem).
// Read slots/iter: ph7:12(A-M0,B-N0) ph0:4(B-N1) ph1:8(A-M1) ph3:12 ph4:4 ph5:8
// lgkm counts:          ph0:4 ph1:8 ph2:0 ph3:12 ph4:4 ph5:8 ph6:0 ph7:12
// Stage slots (2x gload16 each): S2@ph1(b0.A0) S3@ph2(b0.B0) S4@ph3(b0.B1)
//   S5@ph4(b0.A1) S6@ph5(b1.A0) S7@ph6(b1.B0) S8+S1'@ph7(b1.B1, b1.A1)
// vmcnt(4) guarantee points at end-ph2 / end-ph6 (retire all but last 2 stage
// ops). Hazard ledger verified: every staged half vm-retires >=1 barrier before
// its first read issues; every half's reads lgkm-retire >=1 barrier before the
// overwriting stage issues; register WAR safe (A 2 gens, B 1 gen w/ deferred N1).
// ---------------------------------------------------------------------------

#define MQ(MH, NH, G, LGSTR) do {                                                    \
    asm volatile("s_waitcnt lgkmcnt(" LGSTR ")" ::: "memory");                       \
    __builtin_amdgcn_sched_barrier(0);                                               \
    __builtin_amdgcn_s_setprio(1);                                                   \
    _Pragma("unroll")                                                                \
    for (int m4 = 0; m4 < 4; ++m4) {                                                 \
        _Pragma("unroll")                                                            \
        for (int n2 = 0; n2 < 2; ++n2) {                                             \
            _Pragma("unroll")                                                        \
            for (int ks = 0; ks < 2; ++ks)                                           \
                acc[(MH) * 4 + m4][(NH) * 2 + n2] =                                  \
                    __builtin_amdgcn_mfma_f32_16x16x32_f16(                          \
                        aS[G][m4][ks], bS[NH][n2][ks],                               \
                        acc[(MH) * 4 + m4][(NH) * 2 + n2], 0, 0, 0);                 \
        }                                                                            \
    }                                                                                \
    __builtin_amdgcn_s_setprio(0);                                                   \
} while (0)

template<int ACT, int CIN, bool POOL>
__global__ __launch_bounds__(512, 2) void conv8p(
    const f16* __restrict__ inT, const f16* __restrict__ Wh,
    const float* __restrict__ bias, f16* __restrict__ outT,
    float* __restrict__ st, float* __restrict__ Sp, float* __restrict__ Qp,
    int O, int Tout, int offMul, int Opad)
{
    constexpr bool SPLICE = (CIN == 1536);
    constexpr int NT = CIN / 64;        // K-tiles of 64 channels
    constexpr int nIter = NT / 2;
    __shared__ __align__(16) f16 Ilds[2][8 * 256 * 8];   // 64KB
    __shared__ __align__(16) f16 Wlds[2][8 * 256 * 8];   // 64KB
    __shared__ float redS[8][64];
    __shared__ float redQ[8][64];

    const int tid = threadIdx.x;
    const int lane = tid & 63, wave = tid >> 6;
    const int wt = wave & 1, wo = wave >> 1;              // 2 t-waves x 4 o-waves
    const int quad = lane >> 4, l16 = lane & 15;
    const int tB = blockIdx.x * 256, oB = blockIdx.y * 256, b = blockIdx.z;
    const f16* inb = inT + (size_t)b * 64 * TS * 8;       // input always 512 ch = 64 octets
    const int sBase = oB >> 7;                            // weight slab base
    const int octSel = tid >> 7;                          // 0..3 (uniform per wave)
    const int tPos = tid & 127;

    // block-wide staging: one call = 4 octets x 128 rows x 16B = 8KB; half = 2 calls
    auto stageA = [&](int pb, int kt, int mh) {
#pragma unroll
        for (int cc = 0; cc < 2; ++cc) {
            const int octL = cc * 4 + octSel;
            const int octG = kt * 8 + octL;
            const int t = tB + mh * 128 + tPos;
            const f16* src;
            if constexpr (SPLICE) {
                const int cx = octG >> 6;                 // splice context index
                const int fo = octG & 63;
                src = inb + ((size_t)fo * TS + t + cx * offMul) * 8;
            } else {
                src = inb + ((size_t)octG * TS + t) * 8;
            }
            gload16(src, &Ilds[pb][(octL * 256 + mh * 128 + tPos) * 8]);
        }
    };
    auto stageB = [&](int pb, int kt, int nh) {
#pragma unroll
        for (int cc = 0; cc < 2; ++cc) {
            const int octL = cc * 4 + octSel;
            const f16* src = Wh + (((size_t)(sBase + nh) * (CIN >> 3) + kt * 8 + octL) * 128 + tPos) * 8;
            gload16(src, &Wlds[pb][(octL * 256 + nh * 128 + tPos) * 8]);
        }
    };

    v4f acc[8][4];
#pragma unroll
    for (int m = 0; m < 8; ++m)
#pragma unroll
        for (int n = 0; n < 4; ++n)
#pragma unroll
            for (int r = 0; r < 4; ++r) acc[m][n][r] = 0.f;

    v8h aS[2][4][2];     // A frags, 2 generations (read-ahead)
    v8h bS[2][2][2];     // B frags [nh][n2][ks], single gen (N1 read deferred)

    auto rdA = [&](int pb, int mh, int g) {              // 8 x ds_read_b128
#pragma unroll
        for (int m4 = 0; m4 < 4; ++m4)
#pragma unroll
            for (int ks = 0; ks < 2; ++ks)
                aS[g][m4][ks] = *(const v8h*)&Ilds[pb][((ks * 4 + quad) * 256 +
                    mh * 128 + wt * 64 + m4 * 16 + l16) * 8];
    };
    auto rdB = [&](int pb, int nh) {                     // 4 x ds_read_b128
#pragma unroll
        for (int n2 = 0; n2 < 2; ++n2)
#pragma unroll
            for (int ks = 0; ks < 2; ++ks)
                bS[nh][n2][ks] = *(const v8h*)&Wlds[pb][((ks * 4 + quad) * 256 +
                    nh * 128 + wo * 32 + n2 * 16 + l16) * 8];
    };

    // prologue: buf0 <- kt0 (8 calls), buf1 <- kt1 (8 calls); vmcnt(8) = buf0 done
    stageA(0, 0, 0); stageB(0, 0, 0); stageB(0, 0, 1); stageA(0, 0, 1);
    stageA(1, 1, 0); stageB(1, 1, 0); stageB(1, 1, 1); stageA(1, 1, 1);
    wait_vm8();
    BARRIER;
    rdA(0, 0, 0); rdB(0, 0);          // pre-reads for ph0 (A-M0, B-N0 of buf0)

#pragma unroll 1
    for (int i = 0; i < nIter; ++i) {
        const int kn0 = 2 * i + 2, kn1 = 2 * i + 3;
        const bool more = (i + 1 < nIter);
        // ph0: read B-N1(b0) ahead; MFMA (M0,N0)
        rdB(0, 1);
        BARRIER; MQ(0, 0, 0, "4"); BARRIER;
        // ph1: read A-M1(b0) ahead; stage b0.A0<-kn0; MFMA (M0,N1)
        rdA(0, 1, 1);
        if (more) stageA(0, kn0, 0);
        BARRIER; MQ(0, 1, 0, "8"); BARRIER;
        // ph2: stage b0.B0<-kn0; MFMA (M1,N0); vm guarantee point
        if (more) stageB(0, kn0, 0);
        BARRIER; MQ(1, 0, 1, "0");
        if (more) wait_vm4(); else wait_vm0();
        BARRIER;
        // ph3: read A-M0,B-N0 (b1) ahead; stage b0.B1; MFMA (M1,N1)
        rdA(1, 0, 0); rdB(1, 0);
        if (more) stageB(0, kn0, 1);
        BARRIER; MQ(1, 1, 1, "12"); BARRIER;
        // ph4: read B-N1(b1) ahead; stage b0.A1; MFMA (M0,N0) of b1
        rdB(1, 1);
        if (more) stageA(0, kn0, 1);
        BARRIER; MQ(0, 0, 0, "4"); BARRIER;
        // ph5: read A-M1(b1) ahead; stage b1.A0<-kn1; MFMA (M0,N1)
        rdA(1, 1, 1);
        if (more) stageA(1, kn1, 0);
        BARRIER; MQ(0, 1, 0, "8"); BARRIER;
        // ph6: stage b1.B0<-kn1; MFMA (M1,N0); vm guarantee point
        if (more) stageB(1, kn1, 0);
        BARRIER; MQ(1, 0, 1, "0");
        if (more) wait_vm4();
        BARRIER;
        // ph7: read A-M0,B-N0 (next b0) ahead; stage b1.B1 + b1.A1; MFMA (M1,N1)
        if (more) {
            rdA(0, 0, 0); rdB(0, 0);
            stageB(1, kn1, 1); stageA(1, kn1, 1);
        }
        BARRIER; MQ(1, 1, 1, "12"); BARRIER;
    }

    // epilogue: bias + activation + (store | pool-partials) + per-o sum/sumsq
    float Sl[4] = {0, 0, 0, 0}, Ql[4] = {0, 0, 0, 0};
#pragma unroll
    for (int n = 0; n < 4; ++n) {
        const int oLoc = (n >> 1) * 128 + wo * 32 + (n & 1) * 16 + l16;
        const int o = oB + oLoc;
        const float bs = bias[o];
        f16* orow = nullptr;
        if constexpr (!POOL)
            orow = outT + (size_t)b * O * TS + (size_t)(o >> 3) * TS * 8 + (o & 7);
#pragma unroll
        for (int m = 0; m < 8; ++m)
#pragma unroll
            for (int r = 0; r < 4; ++r) {
                const int t = tB + (m >> 2) * 128 + wt * 64 + (m & 3) * 16 + quad * 4 + r;
                if (t < Tout) {
                    float v = acc[m][n][r] + bs;
                    v = fmaxf(v, 0.f);
                    if (ACT == 2) v = fminf(v, 6.f);
                    if constexpr (!POOL) orow[(size_t)t * 8] = (f16)v;
                    Sl[n] += v; Ql[n] += v * v;
                }
            }
    }
#pragma unroll
    for (int n = 0; n < 4; ++n) {
        float s = Sl[n], q = Ql[n];
        s += __shfl_down(s, 32); q += __shfl_down(q, 32);
        s += __shfl_down(s, 16); q += __shfl_down(q, 16);
        if (lane < 16) { redS[wave][n * 16 + lane] = s; redQ[wave][n * 16 + lane] = q; }
    }
    __syncthreads();
    if (tid < 256) {
        const int rem = tid & 127;
        const int wo2 = rem >> 5;
        const int nn  = (tid >> 7) * 2 + ((rem >> 4) & 1);
        const int l   = tid & 15;
        const float s = redS[wo2 * 2][nn * 16 + l] + redS[wo2 * 2 + 1][nn * 16 + l];
        const float q = redQ[wo2 * 2][nn * 16 + l] + redQ[wo2 * 2 + 1][nn * 16 + l];
        if constexpr (POOL) {
            Sp[((size_t)blockIdx.x * B + b) * Opad + oB + tid] = s;
            Qp[((size_t)blockIdx.x * B + b) * Opad + oB + tid] = q;
        } else {
            atomicAdd(&st[oB + tid], s);
            atomicAdd(&st[512 + oB + tid], q);
        }
    }
}

// bn5 (global over B,T) + per-(b,c) mean/std(ddof=1) -> stat [B, 2*Oreal]
__global__ __launch_bounds__(256) void pool_finalize(
    const float* __restrict__ Sp, const float* __restrict__ Qp,
    const float* __restrict__ g5, const float* __restrict__ b5,
    float* __restrict__ stat, int Opad, int Oreal, int T)
{
    int co = blockIdx.x * 256 + threadIdx.x;
    if (co >= Oreal) return;
    double sS = 0, sQ = 0;
    for (int z = 0; z < 8; ++z)
        for (int b = 0; b < B; ++b) {
            sS += Sp[((size_t)z * B + b) * Opad + co];
            sQ += Qp[((size_t)z * B + b) * Opad + co];
        }
    double invN = 1.0 / ((double)B * T);
    double m = sS * invN;
    double v = sQ * invN - m * m;
    float sc = g5[co] * rsqrtf((float)v + EPSF);
    float sh = b5[co] - (float)m * sc;
    for (int b = 0; b < B; ++b) {
        double sb = 0, qb = 0;
        for (int z = 0; z < 8; ++z) {
            sb += Sp[((size_t)z * B + b) * Opad + co];
            qb += Qp[((size_t)z * B + b) * Opad + co];
        }
        double mb = sb / T;
        double vb = (qb - sb * sb / T) / (T - 1);
        if (vb < 0) vb = 0;
        stat[(size_t)b * 2 * Oreal + co]         = (float)mb * sc + sh;
        stat[(size_t)b * 2 * Oreal + Oreal + co] = sqrtf((float)vb) * fabsf(sc);
    }
}

// wave-per-output FC: y[b,o] = relu6( dot(x[b,:], W[o,:]) + bias[o] )
__global__ __launch_bounds__(256) void fc_relu6(const float* __restrict__ x,
                                                const float* __restrict__ W,
                                                const float* __restrict__ bias,
                                                float* __restrict__ y, int Cin, int O)
{
    int wid = (blockIdx.x * 256 + threadIdx.x) >> 6;
    int lane = threadIdx.x & 63;
    if (wid >= B * O) return;
    int b = wid / O, o = wid - b * O;
    const float* xr = x + (size_t)b * Cin;
    const float* wr = W + (size_t)o * Cin;
    float s = 0.f;
    for (int c = lane; c < Cin; c += 64) s = fmaf(xr[c], wr[c], s);
#pragma unroll
    for (int d = 32; d; d >>= 1) s += __shfl_down(s, d);
    if (lane == 0) y[wid] = fminf(fmaxf(s + bias[o], 0.f), 6.f);
}

// BatchNorm over batch dim on [B, O]
__global__ __launch_bounds__(512) void bn_batch(const float* __restrict__ x,
                                                const float* __restrict__ g,
                                                const float* __restrict__ be,
                                                float* __restrict__ y, int O)
{
    int o = threadIdx.x;
    if (o >= O) return;
    float s = 0.f, q = 0.f;
    for (int b = 0; b < B; ++b) { float v = x[b * O + o]; s += v; q += v * v; }
    float m = s / B;
    float var = q / B - m * m;
    float sc = g[o] * rsqrtf(var + EPSF);
    float sh = be[o] - m * sc;
    for (int b = 0; b < B; ++b) y[b * O + o] = x[b * O + o] * sc + sh;
}

} // anonymous namespace

extern "C" void kernel_launch(void* const* d_in, const int* in_sizes, int n_in,
                              void* d_out, int out_size, void* d_ws, size_t ws_size,
                              hipStream_t stream)
{
    (void)in_sizes; (void)n_in; (void)out_size; (void)ws_size;
    const float* x     = (const float*)d_in[0];
    const float* h1_w  = (const float*)d_in[1];
    const float* h1_b  = (const float*)d_in[2];
    const float* h2_w  = (const float*)d_in[3];
    const float* h2_b  = (const float*)d_in[4];
    const float* bn2_g = (const float*)d_in[5];
    const float* bn2_b = (const float*)d_in[6];
    const float* h3_w  = (const float*)d_in[7];
    const float* h3_b  = (const float*)d_in[8];
    const float* bn3_g = (const float*)d_in[9];
    const float* bn3_b = (const float*)d_in[10];
    const float* h4_w  = (const float*)d_in[11];
    const float* h4_b  = (const float*)d_in[12];
    const float* bn4_g = (const float*)d_in[13];
    const float* bn4_b = (const float*)d_in[14];
    const float* h5_w  = (const float*)d_in[15];
    const float* h5_b  = (const float*)d_in[16];
    const float* bn5_g = (const float*)d_in[17];
    const float* bn5_b = (const float*)d_in[18];
    const float* l1_w  = (const float*)d_in[19];
    const float* l1_b  = (const float*)d_in[20];
    const float* bn6_g = (const float*)d_in[21];
    const float* bn6_b = (const float*)d_in[22];
    const float* l2_w  = (const float*)d_in[23];
    const float* l2_b  = (const float*)d_in[24];
    const float* bn7_g = (const float*)d_in[25];
    const float* bn7_b = (const float*)d_in[26];

    char* ws = (char*)d_ws;
    size_t off = 0;
    auto alloc = [&](size_t bytes) {
        char* p = ws + off;
        off += (bytes + 255) & ~(size_t)255;
        return (void*)p;
    };
    f16* xT    = (f16*)alloc(((size_t)B * 3  * TS * 8 + 2048) * 2);
    f16* bufA  = (f16*)alloc(((size_t)B * 64 * TS * 8 + 2048) * 2);  // o1, later o3
    f16* bufB  = (f16*)alloc(((size_t)B * 64 * TS * 8 + 2048) * 2);  // o2, later o4
    f16* Wh1   = (f16*)alloc((size_t)512 * 128 * 2);
    f16* Wh2   = (f16*)alloc((size_t)512 * 1536 * 2);
    f16* Wh3   = (f16*)alloc((size_t)512 * 1536 * 2);
    f16* Wh4   = (f16*)alloc((size_t)512 * 512 * 2);
    f16* Wh5   = (f16*)alloc((size_t)1536 * 512 * 2);
    float* bf1 = (float*)alloc(512 * 4);
    float* bf2 = (float*)alloc(512 * 4);
    float* bf3 = (float*)alloc(512 * 4);
    float* bf4 = (float*)alloc(512 * 4);
    float* bf5 = (float*)alloc(1536 * 4);
    float* stZ = (float*)alloc(4096 * 4);       // st1..st4, zeroed by transpose_x
    float* st1 = stZ, *st2 = stZ + 1024, *st3 = stZ + 2048, *st4 = stZ + 3072;
    float* Sp  = (float*)alloc((size_t)8 * B * 1536 * 4);
    float* Qp  = (float*)alloc((size_t)8 * B * 1536 * 4);
    float* stat = (float*)alloc((size_t)B * 3000 * 4);
    float* f1  = (float*)alloc((size_t)B * 512 * 4);
    float* f2  = (float*)alloc((size_t)B * 512 * 4);

    transpose_x<<<(B * 3 * TS * 8 + 255) / 256, 256, 0, stream>>>(x, xT, stZ);

    // L1: reorder/cast/swizzle W1 (no prev BN); splice(0..4), Cin pad->128
    fold_mfma<24, 5><<<512, 256, 0, stream>>>(h1_w, h1_b, nullptr, nullptr, nullptr,
                                              Wh1, bf1, 512, 20, 128, 100, 0.f);
    conv_mfma<1, 24, 128><<<dim3(16, 4, B), 256, 0, stream>>>(
        xT, Wh1, bf1, bufA, st1, 512, T1, 1);

    // L2: fold bn1 (no affine); splice(0,2,4) -> 8-phase 256^2 read-ahead kernel
    fold_mfma<512, 3><<<512, 256, 0, stream>>>(h2_w, h2_b, st1, nullptr, nullptr,
                                               Wh2, bf2, 512, 512, 1536, 1536,
                                               1.f / (B * T1));
    conv8p<1, 1536, false><<<dim3(8, 2, B), 512, 0, stream>>>(
        bufA, Wh2, bf2, bufB, st2, nullptr, nullptr, 512, T2, 2, 0);

    // L3: fold bn2; splice(0,3,6)
    fold_mfma<512, 3><<<512, 256, 0, stream>>>(h3_w, h3_b, st2, bn2_g, bn2_b,
                                               Wh3, bf3, 512, 512, 1536, 1536,
                                               1.f / (B * T2));
    conv8p<1, 1536, false><<<dim3(8, 2, B), 512, 0, stream>>>(
        bufB, Wh3, bf3, bufA, st3, nullptr, nullptr, 512, T3, 3, 0);

    // L4: fold bn3; conv 512x512, relu6
    fold_mfma<512, 1><<<512, 256, 0, stream>>>(h4_w, h4_b, st3, bn3_g, bn3_b,
                                               Wh4, bf4, 512, 512, 512, 512,
                                               1.f / (B * T3));
    conv8p<2, 512, false><<<dim3(8, 2, B), 512, 0, stream>>>(
        bufA, Wh4, bf4, bufB, st4, nullptr, nullptr, 512, T3, 0, 0);

    // L5: fold bn4; conv 1500(pad 1536)x512 + relu6 + fused 256-t-zone reduction
    fold_mfma<512, 1><<<1536, 256, 0, stream>>>(h5_w, h5_b, st4, bn4_g, bn4_b,
                                                Wh5, bf5, 1500, 512, 512, 512,
                                                1.f / (B * T3));
    conv8p<2, 512, true><<<dim3(8, 6, B), 512, 0, stream>>>(
        bufB, Wh5, bf5, nullptr, nullptr, Sp, Qp, 1536, T3, 0, 1536);

    // bn5 + stats pooling -> stat [B,3000]
    pool_finalize<<<6, 256, 0, stream>>>(Sp, Qp, bn5_g, bn5_b, stat, 1536, 1500, T3);

    // FC head
    fc_relu6<<<(B * 512 * 64 + 255) / 256, 256, 0, stream>>>(stat, l1_w, l1_b, f1, 3000, 512);
    bn_batch<<<1, 512, 0, stream>>>(f1, bn6_g, bn6_b, f1, 512);
    fc_relu6<<<(B * 512 * 64 + 255) / 256, 256, 0, stream>>>(f1, l2_w, l2_b, f2, 512, 512);
    bn_batch<<<1, 512, 0, stream>>>(f2, bn7_g, bn7_b, (float*)d_out, 512);
}

// Round 3
// 749.605 us; speedup vs baseline: 1.1588x; 1.1588x over previous
//
#include <hip/hip_runtime.h>
#include <cstdint>

#define EPSF 1e-5f

namespace {

typedef _Float16 f16;
typedef _Float16 v8h __attribute__((ext_vector_type(8)));
typedef float v4f __attribute__((ext_vector_type(4)));

constexpr int B  = 32;
constexpr int T0 = 2048, F0 = 20;
constexpr int T1 = 2044, T2 = 2040, T3 = 2034;
constexpr int TS = 2048;   // uniform stored t-rows per (b, channel-octet)

// async global->LDS DMA, 16B per lane; LDS dest = wave-uniform base + lane*16
__device__ __forceinline__ void gload16(const void* g, void* l) {
    typedef const __attribute__((address_space(1))) void* gp_t;
    typedef __attribute__((address_space(3))) void* lp_t;
    __builtin_amdgcn_global_load_lds((gp_t)(unsigned long long)g,
                                     (lp_t)(unsigned int)(unsigned long long)l,
                                     16, 0, 0);
}
__device__ __forceinline__ void wait_vm4() { asm volatile("s_waitcnt vmcnt(4)" ::: "memory"); }
__device__ __forceinline__ void wait_vm0() { asm volatile("s_waitcnt vmcnt(0)" ::: "memory"); }

#define BARRIER asm volatile("s_barrier" ::: "memory")
#define VMW(N)  asm volatile("s_waitcnt vmcnt(" #N ")" ::: "memory")

// x [B, T0, F0] fp32 -> xT [b][3 oct][TS][8] fp16; first blocks also zero st[4096]
__global__ __launch_bounds__(256) void transpose_x(const float* __restrict__ x,
                                                   f16* __restrict__ xT,
                                                   float* __restrict__ stZ)
{
    int idx = blockIdx.x * 256 + threadIdx.x;
    if (idx < 4096) stZ[idx] = 0.f;            // zero st1..st4 (atomic stats targets)
    constexpr int total = B * 3 * TS * 8;
    if (idx >= total) return;
    int fl = idx & 7;
    int t  = (idx >> 3) & (TS - 1);
    int fo = (idx >> 14) % 3;
    int b  = idx / (3 << 14);
    int f  = fo * 8 + fl;
    float v = (f < F0) ? x[((size_t)b * T0 + t) * F0 + f] : 0.f;
    xT[idx] = (f16)v;
}

// Fold prev-layer BN into weights, cast fp16, reorder K c-major (k = c*FP + f),
// write SWIZZLED slab order [o/128][k/8][o%128][8]. FP,C compile-time -> no v_rcp divs.
template<int FP, int C>
__global__ __launch_bounds__(256) void fold_mfma(
    const float* __restrict__ W, const float* __restrict__ bias,
    const float* __restrict__ st, const float* __restrict__ gamma, const float* __restrict__ beta,
    f16* __restrict__ Wh, float* __restrict__ bf,
    int Oreal, int Freal, int Cin, int CinOrig, float invN)
{
    int o = blockIdx.x;
    auto sidx = [&](int k) {
        return ((size_t)((o >> 7) * (Cin >> 3) + (k >> 3)) * 128 + (o & 127)) * 8 + (k & 7);
    };
    if (o >= Oreal) {
        for (int k = threadIdx.x; k < Cin; k += 256) Wh[sidx(k)] = (f16)0.f;
        if (threadIdx.x == 0) bf[o] = 0.f;
        return;
    }
    float local = 0.f;
    for (int k = threadIdx.x; k < Cin; k += 256) {
        int c = k / FP, f = k - c * FP;        // FP constexpr -> magic-mul/shift
        float wv = 0.f;
        if (c < C && f < Freal) {
            float sc = 1.f, sh = 0.f;
            if (st) {
                float mean = st[f] * invN;
                float var  = st[Freal + f] * invN - mean * mean;
                sc = rsqrtf(var + EPSF);
                if (gamma) sc *= gamma[f];
                sh = (beta ? beta[f] : 0.f) - mean * sc;
            }
            float w = W[(size_t)o * CinOrig + f * C + c];
            wv = w * sc;
            local += w * sh;
        }
        Wh[sidx(k)] = (f16)wv;
    }
#pragma unroll
    for (int d = 32; d; d >>= 1) local += __shfl_down(local, d);
    __shared__ float red[4];
    if ((threadIdx.x & 63) == 0) red[threadIdx.x >> 6] = local;
    __syncthreads();
    if (threadIdx.x == 0) bf[o] = bias[o] + red[0] + red[1] + red[2] + red[3];
}

// L1 only (CIN=128): fused splice+conv via MFMA, 128x128 tile, 2-phase pipeline.
template<int ACT, int FPR, int CIN>
__global__ __launch_bounds__(256, 4) void conv_mfma(
    const f16* __restrict__ inT, const f16* __restrict__ Wh,
    const float* __restrict__ bias, f16* __restrict__ outT,
    float* __restrict__ st, int O, int Tout, int offMul)
{
    __shared__ __align__(16) f16 Ilds[2][4 * 128 * 8];
    __shared__ __align__(16) f16 Wlds[2][4 * 128 * 8];
    __shared__ float redS[2][128];
    __shared__ float redQ[2][128];
    const int tid  = threadIdx.x;
    const int lane = tid & 63, wave = tid >> 6;
    const int wt = wave & 1, wo = wave >> 1;
    const int quad = lane >> 4, l16 = lane & 15;
    const int tB = blockIdx.x * 128, oB = blockIdx.y * 128, b = blockIdx.z;
    const f16* inb = inT + (size_t)b * FPR * TS;
    const size_t wBase = (size_t)(oB >> 7) * (CIN >> 3);

    v4f acc[4][4];
#pragma unroll
    for (int mi = 0; mi < 4; ++mi)
#pragma unroll
        for (int ni = 0; ni < 4; ++ni)
#pragma unroll
            for (int r = 0; r < 4; ++r) acc[mi][ni][r] = 0.f;

    constexpr int nIter = CIN >> 5;

    auto compute = [&](int pb) {
        v8h afr[4], bfr[4];
#pragma unroll
        for (int mi = 0; mi < 4; ++mi)
            afr[mi] = *(const v8h*)&Ilds[pb][(quad * 128 + wt * 64 + mi * 16 + l16) * 8];
#pragma unroll
        for (int ni = 0; ni < 4; ++ni)
            bfr[ni] = *(const v8h*)&Wlds[pb][(quad * 128 + wo * 64 + ni * 16 + l16) * 8];
#pragma unroll
        for (int mi = 0; mi < 4; ++mi)
#pragma unroll
            for (int ni = 0; ni < 4; ++ni)
                acc[mi][ni] = __builtin_amdgcn_mfma_f32_16x16x32_f16(
                    afr[mi], bfr[ni], acc[mi][ni], 0, 0, 0);
    };

    auto stage = [&](int iB, int pb) {
#pragma unroll
        for (int j = 0; j < 4; ++j) {
            int s = wave * 4 + j;
            int koct = (s & 7) >> 1, half = s & 1;
            if (s < 8) {
                int kidx = iB + koct * 8;
                int c = kidx / FPR, f = kidx - c * FPR;
                int t = tB + half * 64 + lane + c * offMul;
                gload16(inb + ((size_t)(f >> 3) * TS + t) * 8,
                        &Ilds[pb][(koct * 128 + half * 64) * 8]);
            } else {
                gload16(Wh + ((wBase + (iB >> 3) + koct) * 128 + half * 64 + lane) * 8,
                        &Wlds[pb][(koct * 128 + half * 64) * 8]);
            }
        }
    };
    stage(0, 0);
#pragma unroll 2
    for (int k = 0; k < nIter; ++k) {
        const int pb = k & 1;
        __syncthreads();
        if (k + 1 < nIter) { stage((k + 1) * 32, pb ^ 1); wait_vm4(); }
        else               { wait_vm0(); }
        __syncthreads();
        compute(pb);
    }

    float Sl[4] = {0, 0, 0, 0}, Ql[4] = {0, 0, 0, 0};
#pragma unroll
    for (int ni = 0; ni < 4; ++ni) {
        const int o  = oB + wo * 64 + ni * 16 + l16;
        const float bs = bias[o];
        f16* orow = outT + (size_t)b * O * TS + (size_t)(o >> 3) * TS * 8 + (o & 7);
#pragma unroll
        for (int mi = 0; mi < 4; ++mi)
#pragma unroll
            for (int r = 0; r < 4; ++r) {
                int t = tB + wt * 64 + mi * 16 + quad * 4 + r;
                if (t < Tout) {
                    float v = acc[mi][ni][r] + bs;
                    v = fmaxf(v, 0.f);
                    if (ACT == 2) v = fminf(v, 6.f);
                    orow[(size_t)t * 8] = (f16)v;
                    Sl[ni] += v; Ql[ni] += v * v;
                }
            }
    }
#pragma unroll
    for (int ni = 0; ni < 4; ++ni) {
        float s = Sl[ni], q = Ql[ni];
        s += __shfl_down(s, 32); q += __shfl_down(q, 32);
        s += __shfl_down(s, 16); q += __shfl_down(q, 16);
        if (lane < 16) {
            redS[wt][wo * 64 + ni * 16 + lane] = s;
            redQ[wt][wo * 64 + ni * 16 + lane] = q;
        }
    }
    __syncthreads();
    if (tid < 128) {
        atomicAdd(&st[oB + tid],       redS[0][tid] + redS[1][tid]);
        atomicAdd(&st[512 + oB + tid], redQ[0][tid] + redQ[1][tid]);
    }
}

// ---------------------------------------------------------------------------
// 256t x 128o tile, 8-wave, 4-phase MFMA conv with one-phase register
// read-ahead (R2 post-mortem: acc=64 AGPR frees the VGPR budget so the
// double-banked fragments fit WITHOUT spilling; 512-thread blocks cap at
// 256 unified regs/thread).
// Per iter = 2 K-tiles (buf0: even, buf1: odd), 4 phases of 16 MFMA:
//   ph0: MFMA(buf0,Mh0) a0,b0 | reads a1<-buf0.Mh1      | stage f1,e2,e3 (n1)
//   ph1: MFMA(buf0,Mh1) a1,b0 | reads a0<-buf1.Mh0, bB1 | stage c0,c1,d0 (n0)
//   ph2: MFMA(buf1,Mh0) a0,b1 | reads a1<-buf1.Mh1      | stage d1,c2,c3 (n0)
//   ph3: MFMA(buf1,Mh1) a1,b1 | reads a0<-buf0',bB0     | stage e0,e1,f0 (n1)
// lgkm counts leave only this phase's reads in flight (8/12/8/12); vmcnt
// counted at phase ends (2/3/2/3), never 0 in steady state. Stage calls are
// 8KB block-wide (all 512 threads, 16B each) through carried pointers
// advanced by uniform strides (splice cx-wrap folded into the stride pick).
// Hazard ledger: every staged call vm-retires + barrier before its readers
// issue; every LDS region's readers lgkm-drain + barrier before overwrite.
// ---------------------------------------------------------------------------

#define MQ(G, BP, MH, LGSTR) do {                                                    \
    asm volatile("s_waitcnt lgkmcnt(" LGSTR ")" ::: "memory");                       \
    __builtin_amdgcn_sched_barrier(0);                                               \
    __builtin_amdgcn_s_setprio(1);                                                   \
    _Pragma("unroll")                                                                \
    for (int m4 = 0; m4 < 4; ++m4) {                                                 \
        _Pragma("unroll")                                                            \
        for (int n2 = 0; n2 < 2; ++n2) {                                             \
            _Pragma("unroll")                                                        \
            for (int ks = 0; ks < 2; ++ks)                                           \
                acc[(MH) * 4 + m4][n2] =                                             \
                    __builtin_amdgcn_mfma_f32_16x16x32_f16(                          \
                        aS[G][m4][ks], bS[BP][n2][ks],                               \
                        acc[(MH) * 4 + m4][n2], 0, 0, 0);                            \
        }                                                                            \
    }                                                                                \
    __builtin_amdgcn_s_setprio(0);                                                   \
} while (0)

template<int ACT, int CIN, bool POOL>
__global__ __launch_bounds__(512, 2) void conv8p(
    const f16* __restrict__ inT, const f16* __restrict__ Wh,
    const float* __restrict__ bias, f16* __restrict__ outT,
    float* __restrict__ st, float* __restrict__ Sp, float* __restrict__ Qp,
    int O, int Tout, int offMul, int Opad)
{
    constexpr bool SPLICE = (CIN == 1536);
    constexpr int NT = CIN / 64;           // K-tiles of 64 channels
    constexpr int nIter = NT / 2;
    constexpr int KOCT = CIN >> 3;
    static_assert(NT >= 4 && (NT & 1) == 0, "");
    __shared__ __align__(16) f16 Ilds[2][8 * 256 * 8];   // A: 32KB per buf
    __shared__ __align__(16) f16 Wlds[2][8 * 128 * 8];   // B: 16KB per buf
    __shared__ float redS[8][32];
    __shared__ float redQ[8][32];

    const int tid = threadIdx.x;
    const int lane = tid & 63, wave = tid >> 6;
    const int wt = wave & 1, wo = wave >> 1;             // 2 t-halves x 4 o-groups
    const int quad = lane >> 4, l16 = lane & 15;
    const int tB = blockIdx.x * 256, oB = blockIdx.y * 128, b = blockIdx.z;
    const f16* inb = inT + (size_t)b * 64 * TS * 8;      // input = 512 ch = 64 octets
    const int sBase = oB >> 7;                           // weight slab index
    const int octSel = tid >> 7;                         // 0..3, wave-uniform
    const int tPos = tid & 127;                          // = (wave&1)*64 + lane

    v4f acc[8][2];
#pragma unroll
    for (int m = 0; m < 8; ++m)
#pragma unroll
        for (int n = 0; n < 2; ++n)
#pragma unroll
            for (int r = 0; r < 4; ++r) acc[m][n][r] = 0.f;

    v8h aS[2][4][2];     // A banks: [gen][m4][ks]  (2 x 32 regs)
    v8h bS[2][2][2];     // B banks: [tile parity][n2][ks] (2 x 16 regs)

    auto rdA = [&](int pb, int mh, int g) {              // 8 x ds_read_b128
#pragma unroll
        for (int m4 = 0; m4 < 4; ++m4)
#pragma unroll
            for (int ks = 0; ks < 2; ++ks)
                aS[g][m4][ks] = *(const v8h*)&Ilds[pb][((ks * 4 + quad) * 256 +
                    mh * 128 + wt * 64 + m4 * 16 + l16) * 8];
    };
    auto rdB = [&](int pb, int bp) {                     // 4 x ds_read_b128
#pragma unroll
        for (int n2 = 0; n2 < 2; ++n2)
#pragma unroll
            for (int ks = 0; ks < 2; ++ks)
                bS[bp][n2][ks] = *(const v8h*)&Wlds[pb][((ks * 4 + quad) * 128 +
                    wo * 32 + n2 * 16 + l16) * 8];
    };

    // LDS destinations (thread-const)
    f16* dA0_0 = &Ilds[0][(octSel * 256 + tPos) * 8];            // octs 0-3, rows 0-127
    f16* dA0_1 = &Ilds[0][((4 + octSel) * 256 + tPos) * 8];      // octs 4-7
    f16* dA0_2 = &Ilds[0][(octSel * 256 + 128 + tPos) * 8];      // rows 128-255
    f16* dA0_3 = &Ilds[0][((4 + octSel) * 256 + 128 + tPos) * 8];
    f16* dA1_0 = &Ilds[1][(octSel * 256 + tPos) * 8];
    f16* dA1_1 = &Ilds[1][((4 + octSel) * 256 + tPos) * 8];
    f16* dA1_2 = &Ilds[1][(octSel * 256 + 128 + tPos) * 8];
    f16* dA1_3 = &Ilds[1][((4 + octSel) * 256 + 128 + tPos) * 8];
    f16* dB0_0 = &Wlds[0][(octSel * 128 + tPos) * 8];
    f16* dB0_1 = &Wlds[0][((4 + octSel) * 128 + tPos) * 8];
    f16* dB1_0 = &Wlds[1][(octSel * 128 + tPos) * 8];
    f16* dB1_1 = &Wlds[1][((4 + octSel) * 128 + tPos) * 8];

    // ---- prologue: stage tile0 (buf0, 6 calls) + tile1 head (buf1, 3 calls)
    gload16(inb + ((size_t)octSel * TS + tB + tPos) * 8,           dA0_0);  // c0
    gload16(inb + ((size_t)(octSel + 4) * TS + tB + tPos) * 8,     dA0_1);  // c1
    gload16(inb + ((size_t)octSel * TS + tB + 128 + tPos) * 8,     dA0_2);  // c2
    gload16(inb + ((size_t)(octSel + 4) * TS + tB + 128 + tPos) * 8, dA0_3);// c3
    gload16(Wh + (((size_t)sBase * KOCT + octSel) * 128 + tPos) * 8,   dB0_0); // d0
    gload16(Wh + (((size_t)sBase * KOCT + 4 + octSel) * 128 + tPos) * 8, dB0_1);// d1
    gload16(inb + ((size_t)(8 + octSel) * TS + tB + tPos) * 8,       dA1_0);  // e0
    gload16(inb + ((size_t)(12 + octSel) * TS + tB + tPos) * 8,      dA1_1);  // e1
    gload16(Wh + (((size_t)sBase * KOCT + 8 + octSel) * 128 + tPos) * 8, dB1_0);// f0

    // carried staging pointers: q* -> even tiles (next: tile 2), r* -> odd (next tail: tile 1)
    const char* qA0 = (const char*)(inb + ((size_t)(16 + octSel) * TS + tB + tPos) * 8);
    const char* qA1 = qA0 + (intptr_t)4 * TS * 16;
    const char* qB0 = (const char*)(Wh + (((size_t)sBase * KOCT + 16 + octSel) * 128 + tPos) * 8);
    const char* qB1 = qB0 + 4 * 128 * 16;
    const char* rA0 = (const char*)(inb + ((size_t)(8 + octSel) * TS + tB + tPos) * 8);
    const char* rA1 = rA0 + (intptr_t)4 * TS * 16;
    const char* rB0 = (const char*)(Wh + (((size_t)sBase * KOCT + 8 + octSel) * 128 + tPos) * 8);
    const char* rB1 = rB0 + 4 * 128 * 16;
    const intptr_t dAn = (intptr_t)16 * TS * 16;
    const intptr_t dAx = SPLICE ? ((intptr_t)(-48) * TS + offMul) * 16 : dAn;
    const intptr_t dB  = (intptr_t)16 * 128 * 16;

    VMW(3);          // tile0 landed (leave e0,e1,f0 in flight)
    BARRIER;
    rdA(0, 0, 0);    // a0 <- buf0.Mh0
    rdB(0, 0);       // bB0 <- buf0.B

#pragma unroll 1
    for (int i = 0; i < nIter; ++i) {
        const bool more = (i + 1 < nIter);
        // ---- ph0: MFMA(buf0,Mh0); read a1<-buf0.Mh1; stage f1,e2,e3 (tile 2i+1 tail)
        rdA(0, 1, 1);
        gload16(rB1, dB1_1);          // f1
        gload16(rA0 + 2048, dA1_2);   // e2 (rows 128-255)
        gload16(rA1 + 2048, dA1_3);   // e3
        {   // advance odd-family pointers: tile 2i+1 -> 2i+3
            const intptr_t dA = (SPLICE && (i == 3 || i == 7)) ? dAx : dAn;
            rA0 += dA; rA1 += dA; rB0 += dB; rB1 += dB;
        }
        BARRIER;
        MQ(0, 0, 0, "8");
        VMW(2);                       // retire e0,e1,f0,f1 (ph1 reads them)
        BARRIER;
        // ---- ph1: MFMA(buf0,Mh1); read a0<-buf1.Mh0 + bB1<-buf1.B; stage c0,c1,d0
        rdA(1, 0, 0);
        rdB(1, 1);
        if (more) {
            gload16(qA0, dA0_0);      // c0
            gload16(qA1, dA0_1);      // c1
            gload16(qB0, dB0_0);      // d0
        }
        BARRIER;
        MQ(1, 0, 1, "12");
        if (more) { VMW(3); }         // retire e2,e3 (ph2 reads them)
        else      { VMW(0); }
        BARRIER;
        // ---- ph2: MFMA(buf1,Mh0); read a1<-buf1.Mh1; stage d1,c2,c3
        rdA(1, 1, 1);
        if (more) {
            gload16(qB1, dB0_1);      // d1
            gload16(qA0 + 2048, dA0_2);  // c2
            gload16(qA1 + 2048, dA0_3);  // c3
            const intptr_t dA = (SPLICE && (i == 2 || i == 6)) ? dAx : dAn;
            qA0 += dA; qA1 += dA; qB0 += dB; qB1 += dB;
        }
        BARRIER;
        MQ(0, 1, 0, "8");
        if (more) { VMW(2); }         // retire c0,c1,d0,d1 (ph3 reads them)
        BARRIER;
        // ---- ph3: MFMA(buf1,Mh1); read a0<-buf0'(n0) + bB0; stage e0,e1,f0
        if (more) {
            rdA(0, 0, 0);
            rdB(0, 0);
            gload16(rA0, dA1_0);      // e0
            gload16(rA1, dA1_1);      // e1
            gload16(rB0, dB1_0);      // f0
        }
        BARRIER;
        if (more) { MQ(1, 1, 1, "12"); VMW(3); }   // retire c2,c3 (ph0' reads them)
        else      { MQ(1, 1, 1, "0"); }
        BARRIER;
    }

    // ---- epilogue: bias + activation + (store | pool-partials) + per-o sum/sumsq
    float Sl[2] = {0, 0}, Ql[2] = {0, 0};
#pragma unroll
    for (int n = 0; n < 2; ++n) {
        const int o = oB + wo * 32 + n * 16 + l16;
        const float bs = bias[o];
        f16* orow = nullptr;
        if constexpr (!POOL)
            orow = outT + (size_t)b * O * TS + (size_t)(o >> 3) * TS * 8 + (o & 7);
#pragma unroll
        for (int m = 0; m < 8; ++m)
#pragma unroll
            for (int r = 0; r < 4; ++r) {
                const int t = tB + (m >> 2) * 128 + wt * 64 + (m & 3) * 16 + quad * 4 + r;
                if (t < Tout) {
                    float v = acc[m][n][r] + bs;
                    v = fmaxf(v, 0.f);
                    if (ACT == 2) v = fminf(v, 6.f);
                    if constexpr (!POOL) orow[(size_t)t * 8] = (f16)v;
                    Sl[n] += v; Ql[n] += v * v;
                }
            }
    }
#pragma unroll
    for (int n = 0; n < 2; ++n) {
        float s = Sl[n], q = Ql[n];
        s += __shfl_down(s, 32); q += __shfl_down(q, 32);
        s += __shfl_down(s, 16); q += __shfl_down(q, 16);
        if (lane < 16) { redS[wave][n * 16 + lane] = s; redQ[wave][n * 16 + lane] = q; }
    }
    __syncthreads();
    if (tid < 128) {
        const int wo2 = tid >> 5;
        const int nn  = (tid >> 4) & 1;
        const int l   = tid & 15;
        const float s = redS[wo2 * 2][nn * 16 + l] + redS[wo2 * 2 + 1][nn * 16 + l];
        const float q = redQ[wo2 * 2][nn * 16 + l] + redQ[wo2 * 2 + 1][nn * 16 + l];
        if constexpr (POOL) {
            Sp[((size_t)blockIdx.x * B + b) * Opad + oB + tid] = s;
            Qp[((size_t)blockIdx.x * B + b) * Opad + oB + tid] = q;
        } else {
            atomicAdd(&st[oB + tid], s);
            atomicAdd(&st[512 + oB + tid], q);
        }
    }
}

// bn5 (global over B,T) + per-(b,c) mean/std(ddof=1) -> stat [B, 2*Oreal]
__global__ __launch_bounds__(256) void pool_finalize(
    const float* __restrict__ Sp, const float* __restrict__ Qp,
    const float* __restrict__ g5, const float* __restrict__ b5,
    float* __restrict__ stat, int Opad, int Oreal, int T)
{
    int co = blockIdx.x * 256 + threadIdx.x;
    if (co >= Oreal) return;
    double sS = 0, sQ = 0;
    for (int z = 0; z < 8; ++z)
        for (int b = 0; b < B; ++b) {
            sS += Sp[((size_t)z * B + b) * Opad + co];
            sQ += Qp[((size_t)z * B + b) * Opad + co];
        }
    double invN = 1.0 / ((double)B * T);
    double m = sS * invN;
    double v = sQ * invN - m * m;
    float sc = g5[co] * rsqrtf((float)v + EPSF);
    float sh = b5[co] - (float)m * sc;
    for (int b = 0; b < B; ++b) {
        double sb = 0, qb = 0;
        for (int z = 0; z < 8; ++z) {
            sb += Sp[((size_t)z * B + b) * Opad + co];
            qb += Qp[((size_t)z * B + b) * Opad + co];
        }
        double mb = sb / T;
        double vb = (qb - sb * sb / T) / (T - 1);
        if (vb < 0) vb = 0;
        stat[(size_t)b * 2 * Oreal + co]         = (float)mb * sc + sh;
        stat[(size_t)b * 2 * Oreal + Oreal + co] = sqrtf((float)vb) * fabsf(sc);
    }
}

// wave-per-output FC: y[b,o] = relu6( dot(x[b,:], W[o,:]) + bias[o] )
__global__ __launch_bounds__(256) void fc_relu6(const float* __restrict__ x,
                                                const float* __restrict__ W,
                                                const float* __restrict__ bias,
                                                float* __restrict__ y, int Cin, int O)
{
    int wid = (blockIdx.x * 256 + threadIdx.x) >> 6;
    int lane = threadIdx.x & 63;
    if (wid >= B * O) return;
    int b = wid / O, o = wid - b * O;
    const float* xr = x + (size_t)b * Cin;
    const float* wr = W + (size_t)o * Cin;
    float s = 0.f;
    for (int c = lane; c < Cin; c += 64) s = fmaf(xr[c], wr[c], s);
#pragma unroll
    for (int d = 32; d; d >>= 1) s += __shfl_down(s, d);
    if (lane == 0) y[wid] = fminf(fmaxf(s + bias[o], 0.f), 6.f);
}

// BatchNorm over batch dim on [B, O]
__global__ __launch_bounds__(512) void bn_batch(const float* __restrict__ x,
                                                const float* __restrict__ g,
                                                const float* __restrict__ be,
                                                float* __restrict__ y, int O)
{
    int o = threadIdx.x;
    if (o >= O) return;
    float s = 0.f, q = 0.f;
    for (int b = 0; b < B; ++b) { float v = x[b * O + o]; s += v; q += v * v; }
    float m = s / B;
    float var = q / B - m * m;
    float sc = g[o] * rsqrtf(var + EPSF);
    float sh = be[o] - m * sc;
    for (int b = 0; b < B; ++b) y[b * O + o] = x[b * O + o] * sc + sh;
}

} // anonymous namespace

extern "C" void kernel_launch(void* const* d_in, const int* in_sizes, int n_in,
                              void* d_out, int out_size, void* d_ws, size_t ws_size,
                              hipStream_t stream)
{
    (void)in_sizes; (void)n_in; (void)out_size; (void)ws_size;
    const float* x     = (const float*)d_in[0];
    const float* h1_w  = (const float*)d_in[1];
    const float* h1_b  = (const float*)d_in[2];
    const float* h2_w  = (const float*)d_in[3];
    const float* h2_b  = (const float*)d_in[4];
    const float* bn2_g = (const float*)d_in[5];
    const float* bn2_b = (const float*)d_in[6];
    const float* h3_w  = (const float*)d_in[7];
    const float* h3_b  = (const float*)d_in[8];
    const float* bn3_g = (const float*)d_in[9];
    const float* bn3_b = (const float*)d_in[10];
    const float* h4_w  = (const float*)d_in[11];
    const float* h4_b  = (const float*)d_in[12];
    const float* bn4_g = (const float*)d_in[13];
    const float* bn4_b = (const float*)d_in[14];
    const float* h5_w  = (const float*)d_in[15];
    const float* h5_b  = (const float*)d_in[16];
    const float* bn5_g = (const float*)d_in[17];
    const float* bn5_b = (const float*)d_in[18];
    const float* l1_w  = (const float*)d_in[19];
    const float* l1_b  = (const float*)d_in[20];
    const float* bn6_g = (const float*)d_in[21];
    const float* bn6_b = (const float*)d_in[22];
    const float* l2_w  = (const float*)d_in[23];
    const float* l2_b  = (const float*)d_in[24];
    const float* bn7_g = (const float*)d_in[25];
    const float* bn7_b = (const float*)d_in[26];

    char* ws = (char*)d_ws;
    size_t off = 0;
    auto alloc = [&](size_t bytes) {
        char* p = ws + off;
        off += (bytes + 255) & ~(size_t)255;
        return (void*)p;
    };
    f16* xT    = (f16*)alloc(((size_t)B * 3  * TS * 8 + 2048) * 2);
    f16* bufA  = (f16*)alloc(((size_t)B * 64 * TS * 8 + 2048) * 2);  // o1, later o3
    f16* bufB  = (f16*)alloc(((size_t)B * 64 * TS * 8 + 2048) * 2);  // o2, later o4
    f16* Wh1   = (f16*)alloc((size_t)512 * 128 * 2);
    f16* Wh2   = (f16*)alloc((size_t)512 * 1536 * 2);
    f16* Wh3   = (f16*)alloc((size_t)512 * 1536 * 2);
    f16* Wh4   = (f16*)alloc((size_t)512 * 512 * 2);
    f16* Wh5   = (f16*)alloc((size_t)1536 * 512 * 2);
    float* bf1 = (float*)alloc(512 * 4);
    float* bf2 = (float*)alloc(512 * 4);
    float* bf3 = (float*)alloc(512 * 4);
    float* bf4 = (float*)alloc(512 * 4);
    float* bf5 = (float*)alloc(1536 * 4);
    float* stZ = (float*)alloc(4096 * 4);       // st1..st4, zeroed by transpose_x
    float* st1 = stZ, *st2 = stZ + 1024, *st3 = stZ + 2048, *st4 = stZ + 3072;
    float* Sp  = (float*)alloc((size_t)8 * B * 1536 * 4);
    float* Qp  = (float*)alloc((size_t)8 * B * 1536 * 4);
    float* stat = (float*)alloc((size_t)B * 3000 * 4);
    float* f1  = (float*)alloc((size_t)B * 512 * 4);
    float* f2  = (float*)alloc((size_t)B * 512 * 4);

    transpose_x<<<(B * 3 * TS * 8 + 255) / 256, 256, 0, stream>>>(x, xT, stZ);

    // L1: reorder/cast/swizzle W1 (no prev BN); splice(0..4), Cin pad->128
    fold_mfma<24, 5><<<512, 256, 0, stream>>>(h1_w, h1_b, nullptr, nullptr, nullptr,
                                              Wh1, bf1, 512, 20, 128, 100, 0.f);
    conv_mfma<1, 24, 128><<<dim3(16, 4, B), 256, 0, stream>>>(
        xT, Wh1, bf1, bufA, st1, 512, T1, 1);

    // L2: fold bn1 (no affine); splice(0,2,4) -> 4-phase read-ahead kernel
    fold_mfma<512, 3><<<512, 256, 0, stream>>>(h2_w, h2_b, st1, nullptr, nullptr,
                                               Wh2, bf2, 512, 512, 1536, 1536,
                                               1.f / (B * T1));
    conv8p<1, 1536, false><<<dim3(8, 4, B), 512, 0, stream>>>(
        bufA, Wh2, bf2, bufB, st2, nullptr, nullptr, 512, T2, 2, 0);

    // L3: fold bn2; splice(0,3,6)
    fold_mfma<512, 3><<<512, 256, 0, stream>>>(h3_w, h3_b, st2, bn2_g, bn2_b,
                                               Wh3, bf3, 512, 512, 1536, 1536,
                                               1.f / (B * T2));
    conv8p<1, 1536, false><<<dim3(8, 4, B), 512, 0, stream>>>(
        bufB, Wh3, bf3, bufA, st3, nullptr, nullptr, 512, T3, 3, 0);

    // L4: fold bn3; conv 512x512, relu6
    fold_mfma<512, 1><<<512, 256, 0, stream>>>(h4_w, h4_b, st3, bn3_g, bn3_b,
                                               Wh4, bf4, 512, 512, 512, 512,
                                               1.f / (B * T3));
    conv8p<2, 512, false><<<dim3(8, 4, B), 512, 0, stream>>>(
        bufA, Wh4, bf4, bufB, st4, nullptr, nullptr, 512, T3, 0, 0);

    // L5: fold bn4; conv 1500(pad 1536)x512 + relu6 + fused 256-t-zone reduction
    fold_mfma<512, 1><<<1536, 256, 0, stream>>>(h5_w, h5_b, st4, bn4_g, bn4_b,
                                                Wh5, bf5, 1500, 512, 512, 512,
                                                1.f / (B * T3));
    conv8p<2, 512, true><<<dim3(8, 12, B), 512, 0, stream>>>(
        bufB, Wh5, bf5, nullptr, nullptr, Sp, Qp, 1536, T3, 0, 1536);

    // bn5 + stats pooling -> stat [B,3000]
    pool_finalize<<<6, 256, 0, stream>>>(Sp, Qp, bn5_g, bn5_b, stat, 1536, 1500, T3);

    // FC head
    fc_relu6<<<(B * 512 * 64 + 255) / 256, 256, 0, stream>>>(stat, l1_w, l1_b, f1, 3000, 512);
    bn_batch<<<1, 512, 0, stream>>>(f1, bn6_g, bn6_b, f1, 512);
    fc_relu6<<<(B * 512 * 64 + 255) / 256, 256, 0, stream>>>(f1, l2_w, l2_b, f2, 512, 512);
    bn_batch<<<1, 512, 0, stream>>>(f2, bn7_g, bn7_b, (float*)d_out, 512);
}

// Round 4
// 706.802 us; speedup vs baseline: 1.2289x; 1.0606x over previous
//
#include <hip/hip_runtime.h>
#include <cstdint>

#define EPSF 1e-5f

namespace {

typedef _Float16 f16;
typedef _Float16 v8h __attribute__((ext_vector_type(8)));
typedef float v4f __attribute__((ext_vector_type(4)));

constexpr int B  = 32;
constexpr int T0 = 2048, F0 = 20;
constexpr int T1 = 2044, T2 = 2040, T3 = 2034;
constexpr int TS = 2048;   // uniform stored t-rows per (b, channel-octet)

// async global->LDS DMA, 16B per lane; LDS dest = wave-uniform base + lane*16
__device__ __forceinline__ void gload16(const void* g, void* l) {
    typedef const __attribute__((address_space(1))) void* gp_t;
    typedef __attribute__((address_space(3))) void* lp_t;
    __builtin_amdgcn_global_load_lds((gp_t)(unsigned long long)g,
                                     (lp_t)(unsigned int)(unsigned long long)l,
                                     16, 0, 0);
}
__device__ __forceinline__ void wait_vm6() { asm volatile("s_waitcnt vmcnt(6)" ::: "memory"); }
__device__ __forceinline__ void wait_vm4() { asm volatile("s_waitcnt vmcnt(4)" ::: "memory"); }
__device__ __forceinline__ void wait_vm0() { asm volatile("s_waitcnt vmcnt(0)" ::: "memory"); }

// x [B, T0, F0] fp32 -> xT [b][3 oct][TS][8] fp16; first blocks also zero st[4096]
__global__ __launch_bounds__(256) void transpose_x(const float* __restrict__ x,
                                                   f16* __restrict__ xT,
                                                   float* __restrict__ stZ)
{
    int idx = blockIdx.x * 256 + threadIdx.x;
    if (idx < 4096) stZ[idx] = 0.f;            // zero st1..st4 (atomic stats targets)
    constexpr int total = B * 3 * TS * 8;
    if (idx >= total) return;
    int fl = idx & 7;
    int t  = (idx >> 3) & (TS - 1);
    int fo = (idx >> 14) % 3;
    int b  = idx / (3 << 14);
    int f  = fo * 8 + fl;
    float v = (f < F0) ? x[((size_t)b * T0 + t) * F0 + f] : 0.f;
    xT[idx] = (f16)v;
}

// Fold prev-layer BN into weights, cast fp16, reorder K c-major (k = c*FP + f),
// write SWIZZLED slab order [o/128][k/8][o%128][8]. FP,C compile-time -> no v_rcp divs.
template<int FP, int C>
__global__ __launch_bounds__(256) void fold_mfma(
    const float* __restrict__ W, const float* __restrict__ bias,
    const float* __restrict__ st, const float* __restrict__ gamma, const float* __restrict__ beta,
    f16* __restrict__ Wh, float* __restrict__ bf,
    int Oreal, int Freal, int Cin, int CinOrig, float invN)
{
    int o = blockIdx.x;
    auto sidx = [&](int k) {
        return ((size_t)((o >> 7) * (Cin >> 3) + (k >> 3)) * 128 + (o & 127)) * 8 + (k & 7);
    };
    if (o >= Oreal) {
        for (int k = threadIdx.x; k < Cin; k += 256) Wh[sidx(k)] = (f16)0.f;
        if (threadIdx.x == 0) bf[o] = 0.f;
        return;
    }
    float local = 0.f;
    for (int k = threadIdx.x; k < Cin; k += 256) {
        int c = k / FP, f = k - c * FP;        // FP constexpr -> magic-mul/shift
        float wv = 0.f;
        if (c < C && f < Freal) {
            float sc = 1.f, sh = 0.f;
            if (st) {
                float mean = st[f] * invN;
                float var  = st[Freal + f] * invN - mean * mean;
                sc = rsqrtf(var + EPSF);
                if (gamma) sc *= gamma[f];
                sh = (beta ? beta[f] : 0.f) - mean * sc;
            }
            float w = W[(size_t)o * CinOrig + f * C + c];
            wv = w * sc;
            local += w * sh;
        }
        Wh[sidx(k)] = (f16)wv;
    }
#pragma unroll
    for (int d = 32; d; d >>= 1) local += __shfl_down(local, d);
    __shared__ float red[4];
    if ((threadIdx.x & 63) == 0) red[threadIdx.x >> 6] = local;
    __syncthreads();
    if (threadIdx.x == 0) bf[o] = bias[o] + red[0] + red[1] + red[2] + red[3];
}

// L1 only (CIN=128): fused splice+conv via MFMA, 128x128 tile, 2-phase pipeline.
template<int ACT, int FPR, int CIN>
__global__ __launch_bounds__(256, 4) void conv_mfma(
    const f16* __restrict__ inT, const f16* __restrict__ Wh,
    const float* __restrict__ bias, f16* __restrict__ outT,
    float* __restrict__ st, int O, int Tout, int offMul)
{
    __shared__ __align__(16) f16 Ilds[2][4 * 128 * 8];
    __shared__ __align__(16) f16 Wlds[2][4 * 128 * 8];
    __shared__ float redS[2][128];
    __shared__ float redQ[2][128];
    const int tid  = threadIdx.x;
    const int lane = tid & 63, wave = tid >> 6;
    const int wt = wave & 1, wo = wave >> 1;
    const int quad = lane >> 4, l16 = lane & 15;
    const int tB = blockIdx.x * 128, oB = blockIdx.y * 128, b = blockIdx.z;
    const f16* inb = inT + (size_t)b * FPR * TS;
    const size_t wBase = (size_t)(oB >> 7) * (CIN >> 3);

    v4f acc[4][4];
#pragma unroll
    for (int mi = 0; mi < 4; ++mi)
#pragma unroll
        for (int ni = 0; ni < 4; ++ni)
#pragma unroll
            for (int r = 0; r < 4; ++r) acc[mi][ni][r] = 0.f;

    constexpr int nIter = CIN >> 5;

    auto compute = [&](int pb) {
        v8h afr[4], bfr[4];
#pragma unroll
        for (int mi = 0; mi < 4; ++mi)
            afr[mi] = *(const v8h*)&Ilds[pb][(quad * 128 + wt * 64 + mi * 16 + l16) * 8];
#pragma unroll
        for (int ni = 0; ni < 4; ++ni)
            bfr[ni] = *(const v8h*)&Wlds[pb][(quad * 128 + wo * 64 + ni * 16 + l16) * 8];
#pragma unroll
        for (int mi = 0; mi < 4; ++mi)
#pragma unroll
            for (int ni = 0; ni < 4; ++ni)
                acc[mi][ni] = __builtin_amdgcn_mfma_f32_16x16x32_f16(
                    afr[mi], bfr[ni], acc[mi][ni], 0, 0, 0);
    };

    auto stage = [&](int iB, int pb) {
#pragma unroll
        for (int j = 0; j < 4; ++j) {
            int s = wave * 4 + j;
            int koct = (s & 7) >> 1, half = s & 1;
            if (s < 8) {
                int kidx = iB + koct * 8;
                int c = kidx / FPR, f = kidx - c * FPR;
                int t = tB + half * 64 + lane + c * offMul;
                gload16(inb + ((size_t)(f >> 3) * TS + t) * 8,
                        &Ilds[pb][(koct * 128 + half * 64) * 8]);
            } else {
                gload16(Wh + ((wBase + (iB >> 3) + koct) * 128 + half * 64 + lane) * 8,
                        &Wlds[pb][(koct * 128 + half * 64) * 8]);
            }
        }
    };
    stage(0, 0);
#pragma unroll 2
    for (int k = 0; k < nIter; ++k) {
        const int pb = k & 1;
        __syncthreads();
        if (k + 1 < nIter) { stage((k + 1) * 32, pb ^ 1); wait_vm4(); }
        else               { wait_vm0(); }
        __syncthreads();
        compute(pb);
    }

    float Sl[4] = {0, 0, 0, 0}, Ql[4] = {0, 0, 0, 0};
#pragma unroll
    for (int ni = 0; ni < 4; ++ni) {
        const int o  = oB + wo * 64 + ni * 16 + l16;
        const float bs = bias[o];
        f16* orow = outT + (size_t)b * O * TS + (size_t)(o >> 3) * TS * 8 + (o & 7);
#pragma unroll
        for (int mi = 0; mi < 4; ++mi)
#pragma unroll
            for (int r = 0; r < 4; ++r) {
                int t = tB + wt * 64 + mi * 16 + quad * 4 + r;
                if (t < Tout) {
                    float v = acc[mi][ni][r] + bs;
                    v = fmaxf(v, 0.f);
                    if (ACT == 2) v = fminf(v, 6.f);
                    orow[(size_t)t * 8] = (f16)v;
                    Sl[ni] += v; Ql[ni] += v * v;
                }
            }
    }
#pragma unroll
    for (int ni = 0; ni < 4; ++ni) {
        float s = Sl[ni], q = Ql[ni];
        s += __shfl_down(s, 32); q += __shfl_down(q, 32);
        s += __shfl_down(s, 16); q += __shfl_down(q, 16);
        if (lane < 16) {
            redS[wt][wo * 64 + ni * 16 + lane] = s;
            redQ[wt][wo * 64 + ni * 16 + lane] = q;
        }
    }
    __syncthreads();
    if (tid < 128) {
        atomicAdd(&st[oB + tid],       redS[0][tid] + redS[1][tid]);
        atomicAdd(&st[512 + oB + tid], redQ[0][tid] + redQ[1][tid]);
    }
}

// ---------------------------------------------------------------------------
// R4: 256t x 128o tile, 256 threads (4 waves, 2x2), 2 BLOCKS/CU.
// Geometry fix from the R1-R3 ledger: wave output = 128t x 64o (acc 8x4 =
// 128 regs, legal at 2 waves/SIMD = 256-reg budget), so LDS reads/MFMA =
// 12/32 = 0.375 (baseline was 0.5, R3 was 0.625). Per-CU per 32-ch K-step:
// MFMA 1024 cy/SIMD vs LDS ~1540 cy -> structural cap 67%, and the PROVEN
// baseline mechanism (2-phase + counted vmcnt + multi-block overlap, m114)
// converts it. No hand lgkm waits, no lockstep phases - the compiler's
// scheduling of the 2-phase skeleton is the known-good path.
// LDS: I 2x16KB + W 2x8KB + red 2KB = 50KB -> 2 blocks/CU (reg-capped).
// Staging: 6 block-wide gload16/K-step (4 A-octets + 2 B-octet-pairs),
// vmcnt(6) leaves next stage in flight, requires current landed.
// ---------------------------------------------------------------------------
template<int ACT, int CIN, bool POOL>
__global__ __launch_bounds__(256, 2) void conv2b(
    const f16* __restrict__ inT, const f16* __restrict__ Wh,
    const float* __restrict__ bias, f16* __restrict__ outT,
    float* __restrict__ st, float* __restrict__ Sp, float* __restrict__ Qp,
    int O, int Tout, int offMul, int Opad)
{
    constexpr int nIter = CIN >> 5;        // 32-ch (4-octet) K-steps
    constexpr int KOCT  = CIN >> 3;
    __shared__ __align__(16) f16 Ilds[2][4 * 256 * 8];   // 16KB per buf
    __shared__ __align__(16) f16 Wlds[2][4 * 128 * 8];   // 8KB per buf
    __shared__ float redS[4][64];
    __shared__ float redQ[4][64];

    const int tid  = threadIdx.x;
    const int lane = tid & 63, wave = tid >> 6;
    const int wt = wave & 1, wo = wave >> 1;             // 2 t-halves x 2 o-halves
    const int quad = lane >> 4, l16 = lane & 15;
    const int tB = blockIdx.x * 256, oB = blockIdx.y * 128, b = blockIdx.z;
    const f16* inb = inT + (size_t)b * 64 * TS * 8;      // input = 512 ch = 64 octets
    const size_t wBase = (size_t)(oB >> 7) * KOCT;

    v4f acc[8][4];
#pragma unroll
    for (int m = 0; m < 8; ++m)
#pragma unroll
        for (int n = 0; n < 4; ++n)
#pragma unroll
            for (int r = 0; r < 4; ++r) acc[m][n][r] = 0.f;

    // block-wide staging: 4 A calls (1 octet x 256 rows each) + 2 B calls
    // (2 octets x 128 rows each); every dest is linear in tid (DMA-legal).
    auto stage = [&](int kt, int pb) {
#pragma unroll
        for (int j = 0; j < 4; ++j) {
            const int g  = kt * 4 + j;                   // global input octet
            const int cx = g >> 6, fo = g & 63;          // splice ctx, feat-octet
            gload16(inb + ((size_t)fo * TS + tB + cx * offMul + tid) * 8,
                    &Ilds[pb][(j * 256 + tid) * 8]);
        }
#pragma unroll
        for (int j = 0; j < 2; ++j) {
            const int g = kt * 4 + 2 * j + (tid >> 7);   // wave-uniform oct select
            gload16(Wh + ((wBase + g) * 128 + (tid & 127)) * 8,
                    &Wlds[pb][(j * 256 + tid) * 8]);
        }
    };

    auto compute = [&](int pb) {
        v8h a[8], w4[4];
#pragma unroll
        for (int m = 0; m < 8; ++m)
            a[m] = *(const v8h*)&Ilds[pb][(quad * 256 + wt * 128 + m * 16 + l16) * 8];
#pragma unroll
        for (int n = 0; n < 4; ++n)
            w4[n] = *(const v8h*)&Wlds[pb][(quad * 128 + wo * 64 + n * 16 + l16) * 8];
#pragma unroll
        for (int m = 0; m < 8; ++m)
#pragma unroll
            for (int n = 0; n < 4; ++n)
                acc[m][n] = __builtin_amdgcn_mfma_f32_16x16x32_f16(
                    a[m], w4[n], acc[m][n], 0, 0, 0);
    };

    stage(0, 0);
#pragma unroll 2
    for (int k = 0; k < nIter; ++k) {
        const int pb = k & 1;
        __syncthreads();
        if (k + 1 < nIter) { stage(k + 1, pb ^ 1); wait_vm6(); }
        else               { wait_vm0(); }
        __syncthreads();
        compute(pb);
    }

    // epilogue: bias + activation + (store | pool) + per-o sum/sumsq
    float Sl[4] = {0, 0, 0, 0}, Ql[4] = {0, 0, 0, 0};
#pragma unroll
    for (int n = 0; n < 4; ++n) {
        const int o  = oB + wo * 64 + n * 16 + l16;
        const float bs = bias[o];
        f16* orow = nullptr;
        if constexpr (!POOL)
            orow = outT + (size_t)b * O * TS + (size_t)(o >> 3) * TS * 8 + (o & 7);
#pragma unroll
        for (int m = 0; m < 8; ++m)
#pragma unroll
            for (int r = 0; r < 4; ++r) {
                const int t = tB + wt * 128 + m * 16 + quad * 4 + r;
                if (t < Tout) {
                    float v = acc[m][n][r] + bs;
                    v = fmaxf(v, 0.f);
                    if (ACT == 2) v = fminf(v, 6.f);
                    if constexpr (!POOL) orow[(size_t)t * 8] = (f16)v;
                    Sl[n] += v; Ql[n] += v * v;
                }
            }
    }
#pragma unroll
    for (int n = 0; n < 4; ++n) {
        float s = Sl[n], q = Ql[n];
        s += __shfl_down(s, 32); q += __shfl_down(q, 32);
        s += __shfl_down(s, 16); q += __shfl_down(q, 16);
        if (lane < 16) { redS[wave][n * 16 + lane] = s; redQ[wave][n * 16 + lane] = q; }
    }
    __syncthreads();
    if (tid < 128) {
        const int wo2 = tid >> 6;                        // o-half
        const float s = redS[wo2 * 2][tid & 63] + redS[wo2 * 2 + 1][tid & 63];
        const float q = redQ[wo2 * 2][tid & 63] + redQ[wo2 * 2 + 1][tid & 63];
        if constexpr (POOL) {
            Sp[((size_t)blockIdx.x * B + b) * Opad + oB + tid] = s;
            Qp[((size_t)blockIdx.x * B + b) * Opad + oB + tid] = q;
        } else {
            atomicAdd(&st[oB + tid], s);
            atomicAdd(&st[512 + oB + tid], q);
        }
    }
}

// bn5 (global over B,T) + per-(b,c) mean/std(ddof=1) -> stat [B, 2*Oreal]
__global__ __launch_bounds__(256) void pool_finalize(
    const float* __restrict__ Sp, const float* __restrict__ Qp,
    const float* __restrict__ g5, const float* __restrict__ b5,
    float* __restrict__ stat, int Opad, int Oreal, int T)
{
    int co = blockIdx.x * 256 + threadIdx.x;
    if (co >= Oreal) return;
    double sS = 0, sQ = 0;
    for (int z = 0; z < 8; ++z)
        for (int b = 0; b < B; ++b) {
            sS += Sp[((size_t)z * B + b) * Opad + co];
            sQ += Qp[((size_t)z * B + b) * Opad + co];
        }
    double invN = 1.0 / ((double)B * T);
    double m = sS * invN;
    double v = sQ * invN - m * m;
    float sc = g5[co] * rsqrtf((float)v + EPSF);
    float sh = b5[co] - (float)m * sc;
    for (int b = 0; b < B; ++b) {
        double sb = 0, qb = 0;
        for (int z = 0; z < 8; ++z) {
            sb += Sp[((size_t)z * B + b) * Opad + co];
            qb += Qp[((size_t)z * B + b) * Opad + co];
        }
        double mb = sb / T;
        double vb = (qb - sb * sb / T) / (T - 1);
        if (vb < 0) vb = 0;
        stat[(size_t)b * 2 * Oreal + co]         = (float)mb * sc + sh;
        stat[(size_t)b * 2 * Oreal + Oreal + co] = sqrtf((float)vb) * fabsf(sc);
    }
}

// wave-per-output FC: y[b,o] = relu6( dot(x[b,:], W[o,:]) + bias[o] )
__global__ __launch_bounds__(256) void fc_relu6(const float* __restrict__ x,
                                                const float* __restrict__ W,
                                                const float* __restrict__ bias,
                                                float* __restrict__ y, int Cin, int O)
{
    int wid = (blockIdx.x * 256 + threadIdx.x) >> 6;
    int lane = threadIdx.x & 63;
    if (wid >= B * O) return;
    int b = wid / O, o = wid - b * O;
    const float* xr = x + (size_t)b * Cin;
    const float* wr = W + (size_t)o * Cin;
    float s = 0.f;
    for (int c = lane; c < Cin; c += 64) s = fmaf(xr[c], wr[c], s);
#pragma unroll
    for (int d = 32; d; d >>= 1) s += __shfl_down(s, d);
    if (lane == 0) y[wid] = fminf(fmaxf(s + bias[o], 0.f), 6.f);
}

// BatchNorm over batch dim on [B, O]
__global__ __launch_bounds__(512) void bn_batch(const float* __restrict__ x,
                                                const float* __restrict__ g,
                                                const float* __restrict__ be,
                                                float* __restrict__ y, int O)
{
    int o = threadIdx.x;
    if (o >= O) return;
    float s = 0.f, q = 0.f;
    for (int b = 0; b < B; ++b) { float v = x[b * O + o]; s += v; q += v * v; }
    float m = s / B;
    float var = q / B - m * m;
    float sc = g[o] * rsqrtf(var + EPSF);
    float sh = be[o] - m * sc;
    for (int b = 0; b < B; ++b) y[b * O + o] = x[b * O + o] * sc + sh;
}

} // anonymous namespace

extern "C" void kernel_launch(void* const* d_in, const int* in_sizes, int n_in,
                              void* d_out, int out_size, void* d_ws, size_t ws_size,
                              hipStream_t stream)
{
    (void)in_sizes; (void)n_in; (void)out_size; (void)ws_size;
    const float* x     = (const float*)d_in[0];
    const float* h1_w  = (const float*)d_in[1];
    const float* h1_b  = (const float*)d_in[2];
    const float* h2_w  = (const float*)d_in[3];
    const float* h2_b  = (const float*)d_in[4];
    const float* bn2_g = (const float*)d_in[5];
    const float* bn2_b = (const float*)d_in[6];
    const float* h3_w  = (const float*)d_in[7];
    const float* h3_b  = (const float*)d_in[8];
    const float* bn3_g = (const float*)d_in[9];
    const float* bn3_b = (const float*)d_in[10];
    const float* h4_w  = (const float*)d_in[11];
    const float* h4_b  = (const float*)d_in[12];
    const float* bn4_g = (const float*)d_in[13];
    const float* bn4_b = (const float*)d_in[14];
    const float* h5_w  = (const float*)d_in[15];
    const float* h5_b  = (const float*)d_in[16];
    const float* bn5_g = (const float*)d_in[17];
    const float* bn5_b = (const float*)d_in[18];
    const float* l1_w  = (const float*)d_in[19];
    const float* l1_b  = (const float*)d_in[20];
    const float* bn6_g = (const float*)d_in[21];
    const float* bn6_b = (const float*)d_in[22];
    const float* l2_w  = (const float*)d_in[23];
    const float* l2_b  = (const float*)d_in[24];
    const float* bn7_g = (const float*)d_in[25];
    const float* bn7_b = (const float*)d_in[26];

    char* ws = (char*)d_ws;
    size_t off = 0;
    auto alloc = [&](size_t bytes) {
        char* p = ws + off;
        off += (bytes + 255) & ~(size_t)255;
        return (void*)p;
    };
    f16* xT    = (f16*)alloc(((size_t)B * 3  * TS * 8 + 2048) * 2);
    f16* bufA  = (f16*)alloc(((size_t)B * 64 * TS * 8 + 2048) * 2);  // o1, later o3
    f16* bufB  = (f16*)alloc(((size_t)B * 64 * TS * 8 + 2048) * 2);  // o2, later o4
    f16* Wh1   = (f16*)alloc((size_t)512 * 128 * 2);
    f16* Wh2   = (f16*)alloc((size_t)512 * 1536 * 2);
    f16* Wh3   = (f16*)alloc((size_t)512 * 1536 * 2);
    f16* Wh4   = (f16*)alloc((size_t)512 * 512 * 2);
    f16* Wh5   = (f16*)alloc((size_t)1536 * 512 * 2);
    float* bf1 = (float*)alloc(512 * 4);
    float* bf2 = (float*)alloc(512 * 4);
    float* bf3 = (float*)alloc(512 * 4);
    float* bf4 = (float*)alloc(512 * 4);
    float* bf5 = (float*)alloc(1536 * 4);
    float* stZ = (float*)alloc(4096 * 4);       // st1..st4, zeroed by transpose_x
    float* st1 = stZ, *st2 = stZ + 1024, *st3 = stZ + 2048, *st4 = stZ + 3072;
    float* Sp  = (float*)alloc((size_t)8 * B * 1536 * 4);
    float* Qp  = (float*)alloc((size_t)8 * B * 1536 * 4);
    float* stat = (float*)alloc((size_t)B * 3000 * 4);
    float* f1  = (float*)alloc((size_t)B * 512 * 4);
    float* f2  = (float*)alloc((size_t)B * 512 * 4);

    transpose_x<<<(B * 3 * TS * 8 + 255) / 256, 256, 0, stream>>>(x, xT, stZ);

    // L1: reorder/cast/swizzle W1 (no prev BN); splice(0..4), Cin pad->128
    fold_mfma<24, 5><<<512, 256, 0, stream>>>(h1_w, h1_b, nullptr, nullptr, nullptr,
                                              Wh1, bf1, 512, 20, 128, 100, 0.f);
    conv_mfma<1, 24, 128><<<dim3(16, 4, B), 256, 0, stream>>>(
        xT, Wh1, bf1, bufA, st1, 512, T1, 1);

    // L2: fold bn1 (no affine); splice(0,2,4) -> fat-wave 2-block kernel
    fold_mfma<512, 3><<<512, 256, 0, stream>>>(h2_w, h2_b, st1, nullptr, nullptr,
                                               Wh2, bf2, 512, 512, 1536, 1536,
                                               1.f / (B * T1));
    conv2b<1, 1536, false><<<dim3(8, 4, B), 256, 0, stream>>>(
        bufA, Wh2, bf2, bufB, st2, nullptr, nullptr, 512, T2, 2, 0);

    // L3: fold bn2; splice(0,3,6)
    fold_mfma<512, 3><<<512, 256, 0, stream>>>(h3_w, h3_b, st2, bn2_g, bn2_b,
                                               Wh3, bf3, 512, 512, 1536, 1536,
                                               1.f / (B * T2));
    conv2b<1, 1536, false><<<dim3(8, 4, B), 256, 0, stream>>>(
        bufB, Wh3, bf3, bufA, st3, nullptr, nullptr, 512, T3, 3, 0);

    // L4: fold bn3; conv 512x512, relu6
    fold_mfma<512, 1><<<512, 256, 0, stream>>>(h4_w, h4_b, st3, bn3_g, bn3_b,
                                               Wh4, bf4, 512, 512, 512, 512,
                                               1.f / (B * T3));
    conv2b<2, 512, false><<<dim3(8, 4, B), 256, 0, stream>>>(
        bufA, Wh4, bf4, bufB, st4, nullptr, nullptr, 512, T3, 0, 0);

    // L5: fold bn4; conv 1500(pad 1536)x512 + relu6 + fused 256-t-zone reduction
    fold_mfma<512, 1><<<1536, 256, 0, stream>>>(h5_w, h5_b, st4, bn4_g, bn4_b,
                                                Wh5, bf5, 1500, 512, 512, 512,
                                                1.f / (B * T3));
    conv2b<2, 512, true><<<dim3(8, 12, B), 256, 0, stream>>>(
        bufB, Wh5, bf5, nullptr, nullptr, Sp, Qp, 1536, T3, 0, 1536);

    // bn5 + stats pooling -> stat [B,3000]
    pool_finalize<<<6, 256, 0, stream>>>(Sp, Qp, bn5_g, bn5_b, stat, 1536, 1500, T3);

    // FC head
    fc_relu6<<<(B * 512 * 64 + 255) / 256, 256, 0, stream>>>(stat, l1_w, l1_b, f1, 3000, 512);
    bn_batch<<<1, 512, 0, stream>>>(f1, bn6_g, bn6_b, f1, 512);
    fc_relu6<<<(B * 512 * 64 + 255) / 256, 256, 0, stream>>>(f1, l2_w, l2_b, f2, 512, 512);
    bn_batch<<<1, 512, 0, stream>>>(f2, bn7_g, bn7_b, (float*)d_out, 512);
}

// Round 5
// 689.611 us; speedup vs baseline: 1.2596x; 1.0249x over previous
//
#include <hip/hip_runtime.h>
#include <cstdint>

#define EPSF 1e-5f

namespace {

typedef _Float16 f16;
typedef _Float16 v8h __attribute__((ext_vector_type(8)));
typedef float v4f __attribute__((ext_vector_type(4)));

constexpr int B  = 32;
constexpr int T0 = 2048, F0 = 20;
constexpr int T1 = 2044, T2 = 2040, T3 = 2034;
constexpr int TS = 2048;   // uniform stored t-rows per (b, channel-octet)

// async global->LDS DMA, 16B per lane; LDS dest = wave-uniform base + lane*16
__device__ __forceinline__ void gload16(const void* g, void* l) {
    typedef const __attribute__((address_space(1))) void* gp_t;
    typedef __attribute__((address_space(3))) void* lp_t;
    __builtin_amdgcn_global_load_lds((gp_t)(unsigned long long)g,
                                     (lp_t)(unsigned int)(unsigned long long)l,
                                     16, 0, 0);
}
__device__ __forceinline__ void wait_vm12() { asm volatile("s_waitcnt vmcnt(12)" ::: "memory"); }
__device__ __forceinline__ void wait_vm6()  { asm volatile("s_waitcnt vmcnt(6)" ::: "memory"); }
__device__ __forceinline__ void wait_vm4()  { asm volatile("s_waitcnt vmcnt(4)" ::: "memory"); }
__device__ __forceinline__ void wait_vm0()  { asm volatile("s_waitcnt vmcnt(0)" ::: "memory"); }

// x [B, T0, F0] fp32 -> xT [b][3 oct][TS][8] fp16; first blocks also zero st[4096]
__global__ __launch_bounds__(256) void transpose_x(const float* __restrict__ x,
                                                   f16* __restrict__ xT,
                                                   float* __restrict__ stZ)
{
    int idx = blockIdx.x * 256 + threadIdx.x;
    if (idx < 4096) stZ[idx] = 0.f;            // zero st1..st4 (atomic stats targets)
    constexpr int total = B * 3 * TS * 8;
    if (idx >= total) return;
    int fl = idx & 7;
    int t  = (idx >> 3) & (TS - 1);
    int fo = (idx >> 14) % 3;
    int b  = idx / (3 << 14);
    int f  = fo * 8 + fl;
    float v = (f < F0) ? x[((size_t)b * T0 + t) * F0 + f] : 0.f;
    xT[idx] = (f16)v;
}

// Fold prev-layer BN into weights, cast fp16, reorder K c-major (k = c*FP + f),
// write SWIZZLED slab order [o/128][k/8][o%128][8]. FP,C compile-time -> no v_rcp divs.
template<int FP, int C>
__global__ __launch_bounds__(256) void fold_mfma(
    const float* __restrict__ W, const float* __restrict__ bias,
    const float* __restrict__ st, const float* __restrict__ gamma, const float* __restrict__ beta,
    f16* __restrict__ Wh, float* __restrict__ bf,
    int Oreal, int Freal, int Cin, int CinOrig, float invN)
{
    int o = blockIdx.x;
    auto sidx = [&](int k) {
        return ((size_t)((o >> 7) * (Cin >> 3) + (k >> 3)) * 128 + (o & 127)) * 8 + (k & 7);
    };
    if (o >= Oreal) {
        for (int k = threadIdx.x; k < Cin; k += 256) Wh[sidx(k)] = (f16)0.f;
        if (threadIdx.x == 0) bf[o] = 0.f;
        return;
    }
    float local = 0.f;
    for (int k = threadIdx.x; k < Cin; k += 256) {
        int c = k / FP, f = k - c * FP;        // FP constexpr -> magic-mul/shift
        float wv = 0.f;
        if (c < C && f < Freal) {
            float sc = 1.f, sh = 0.f;
            if (st) {
                float mean = st[f] * invN;
                float var  = st[Freal + f] * invN - mean * mean;
                sc = rsqrtf(var + EPSF);
                if (gamma) sc *= gamma[f];
                sh = (beta ? beta[f] : 0.f) - mean * sc;
            }
            float w = W[(size_t)o * CinOrig + f * C + c];
            wv = w * sc;
            local += w * sh;
        }
        Wh[sidx(k)] = (f16)wv;
    }
#pragma unroll
    for (int d = 32; d; d >>= 1) local += __shfl_down(local, d);
    __shared__ float red[4];
    if ((threadIdx.x & 63) == 0) red[threadIdx.x >> 6] = local;
    __syncthreads();
    if (threadIdx.x == 0) bf[o] = bias[o] + red[0] + red[1] + red[2] + red[3];
}

// L1 only (CIN=128): fused splice+conv via MFMA, 128x128 tile, 2-phase pipeline.
template<int ACT, int FPR, int CIN>
__global__ __launch_bounds__(256, 4) void conv_mfma(
    const f16* __restrict__ inT, const f16* __restrict__ Wh,
    const float* __restrict__ bias, f16* __restrict__ outT,
    float* __restrict__ st, int O, int Tout, int offMul)
{
    __shared__ __align__(16) f16 Ilds[2][4 * 128 * 8];
    __shared__ __align__(16) f16 Wlds[2][4 * 128 * 8];
    __shared__ float redS[2][128];
    __shared__ float redQ[2][128];
    const int tid  = threadIdx.x;
    const int lane = tid & 63, wave = tid >> 6;
    const int wt = wave & 1, wo = wave >> 1;
    const int quad = lane >> 4, l16 = lane & 15;
    const int tB = blockIdx.x * 128, oB = blockIdx.y * 128, b = blockIdx.z;
    const f16* inb = inT + (size_t)b * FPR * TS;
    const size_t wBase = (size_t)(oB >> 7) * (CIN >> 3);

    v4f acc[4][4];
#pragma unroll
    for (int mi = 0; mi < 4; ++mi)
#pragma unroll
        for (int ni = 0; ni < 4; ++ni)
#pragma unroll
            for (int r = 0; r < 4; ++r) acc[mi][ni][r] = 0.f;

    constexpr int nIter = CIN >> 5;

    auto compute = [&](int pb) {
        v8h afr[4], bfr[4];
#pragma unroll
        for (int mi = 0; mi < 4; ++mi)
            afr[mi] = *(const v8h*)&Ilds[pb][(quad * 128 + wt * 64 + mi * 16 + l16) * 8];
#pragma unroll
        for (int ni = 0; ni < 4; ++ni)
            bfr[ni] = *(const v8h*)&Wlds[pb][(quad * 128 + wo * 64 + ni * 16 + l16) * 8];
#pragma unroll
        for (int mi = 0; mi < 4; ++mi)
#pragma unroll
            for (int ni = 0; ni < 4; ++ni)
                acc[mi][ni] = __builtin_amdgcn_mfma_f32_16x16x32_f16(
                    afr[mi], bfr[ni], acc[mi][ni], 0, 0, 0);
    };

    auto stage = [&](int iB, int pb) {
#pragma unroll
        for (int j = 0; j < 4; ++j) {
            int s = wave * 4 + j;
            int koct = (s & 7) >> 1, half = s & 1;
            if (s < 8) {
                int kidx = iB + koct * 8;
                int c = kidx / FPR, f = kidx - c * FPR;
                int t = tB + half * 64 + lane + c * offMul;
                gload16(inb + ((size_t)(f >> 3) * TS + t) * 8,
                        &Ilds[pb][(koct * 128 + half * 64) * 8]);
            } else {
                gload16(Wh + ((wBase + (iB >> 3) + koct) * 128 + half * 64 + lane) * 8,
                        &Wlds[pb][(koct * 128 + half * 64) * 8]);
            }
        }
    };
    stage(0, 0);
#pragma unroll 2
    for (int k = 0; k < nIter; ++k) {
        const int pb = k & 1;
        __syncthreads();
        if (k + 1 < nIter) { stage((k + 1) * 32, pb ^ 1); wait_vm4(); }
        else               { wait_vm0(); }
        __syncthreads();
        compute(pb);
    }

    float Sl[4] = {0, 0, 0, 0}, Ql[4] = {0, 0, 0, 0};
#pragma unroll
    for (int ni = 0; ni < 4; ++ni) {
        const int o  = oB + wo * 64 + ni * 16 + l16;
        const float bs = bias[o];
        f16* orow = outT + (size_t)b * O * TS + (size_t)(o >> 3) * TS * 8 + (o & 7);
#pragma unroll
        for (int mi = 0; mi < 4; ++mi)
#pragma unroll
            for (int r = 0; r < 4; ++r) {
                int t = tB + wt * 64 + mi * 16 + quad * 4 + r;
                if (t < Tout) {
                    float v = acc[mi][ni][r] + bs;
                    v = fmaxf(v, 0.f);
                    if (ACT == 2) v = fminf(v, 6.f);
                    orow[(size_t)t * 8] = (f16)v;
                    Sl[ni] += v; Ql[ni] += v * v;
                }
            }
    }
#pragma unroll
    for (int ni = 0; ni < 4; ++ni) {
        float s = Sl[ni], q = Ql[ni];
        s += __shfl_down(s, 32); q += __shfl_down(q, 32);
        s += __shfl_down(s, 16); q += __shfl_down(q, 16);
        if (lane < 16) {
            redS[wt][wo * 64 + ni * 16 + lane] = s;
            redQ[wt][wo * 64 + ni * 16 + lane] = q;
        }
    }
    __syncthreads();
    if (tid < 128) {
        atomicAdd(&st[oB + tid],       redS[0][tid] + redS[1][tid]);
        atomicAdd(&st[512 + oB + tid], redQ[0][tid] + redQ[1][tid]);
    }
}

// ---------------------------------------------------------------------------
// R5 = R4 geometry (256t x 128o tile, 4 waves 2x2, wave acc 8x4, 2 blocks/CU)
// + TRIPLE-BUFFERED staging with 2-K-step-deep counted vmcnt(12).
// R4 post-mortem: ~800 cy/step of unexplained stall matches the 1-phase-deep
// vmcnt(6): stage k issued only ~1000 cy before its consume, while A-tile
// staging misses L2 (per-XCD A working set 8MB > 4MB L2) at ~900 cy HBM
// latency -> zero slack. With stage k issued at iter k-2 (~2400+ cy of
// cover), the vm wait should retire instantly (AITER deep-vmcnt pattern).
// vmcnt per-wave semantics: after issuing stage k+2 (6 calls), outstanding =
// {stage k+1, k+2} = 12 -> vmcnt(12) waits exactly stage k. Drain 12->6->0.
// LDS: 3 x (16KB A + 8KB B) = 72KB + 2KB red -> still 2 blocks/CU.
// ---------------------------------------------------------------------------
template<int ACT, int CIN, bool POOL>
__global__ __launch_bounds__(256, 2) void conv2b(
    const f16* __restrict__ inT, const f16* __restrict__ Wh,
    const float* __restrict__ bias, f16* __restrict__ outT,
    float* __restrict__ st, float* __restrict__ Sp, float* __restrict__ Qp,
    int O, int Tout, int offMul, int Opad)
{
    constexpr int nIter = CIN >> 5;        // 32-ch (4-octet) K-steps
    constexpr int KOCT  = CIN >> 3;
    __shared__ __align__(16) f16 Ilds[3][4 * 256 * 8];   // 16KB per buf
    __shared__ __align__(16) f16 Wlds[3][4 * 128 * 8];   // 8KB per buf
    __shared__ float redS[4][64];
    __shared__ float redQ[4][64];

    const int tid  = threadIdx.x;
    const int lane = tid & 63, wave = tid >> 6;
    const int wt = wave & 1, wo = wave >> 1;             // 2 t-halves x 2 o-halves
    const int quad = lane >> 4, l16 = lane & 15;
    const int tB = blockIdx.x * 256, oB = blockIdx.y * 128, b = blockIdx.z;
    const f16* inb = inT + (size_t)b * 64 * TS * 8;      // input = 512 ch = 64 octets
    const size_t wBase = (size_t)(oB >> 7) * KOCT;

    v4f acc[8][4];
#pragma unroll
    for (int m = 0; m < 8; ++m)
#pragma unroll
        for (int n = 0; n < 4; ++n)
#pragma unroll
            for (int r = 0; r < 4; ++r) acc[m][n][r] = 0.f;

    // block-wide staging: 4 A calls (1 octet x 256 rows each) + 2 B calls
    // (2 octets x 128 rows each); every dest is linear in tid (DMA-legal).
    auto stage = [&](int kt, int pb) {
#pragma unroll
        for (int j = 0; j < 4; ++j) {
            const int g  = kt * 4 + j;                   // global input octet
            const int cx = g >> 6, fo = g & 63;          // splice ctx, feat-octet
            gload16(inb + ((size_t)fo * TS + tB + cx * offMul + tid) * 8,
                    &Ilds[pb][(j * 256 + tid) * 8]);
        }
#pragma unroll
        for (int j = 0; j < 2; ++j) {
            const int g = kt * 4 + 2 * j + (tid >> 7);   // wave-uniform oct select
            gload16(Wh + ((wBase + g) * 128 + (tid & 127)) * 8,
                    &Wlds[pb][(j * 256 + tid) * 8]);
        }
    };

    auto compute = [&](int pb) {
        v8h a[8], w4[4];
#pragma unroll
        for (int m = 0; m < 8; ++m)
            a[m] = *(const v8h*)&Ilds[pb][(quad * 256 + wt * 128 + m * 16 + l16) * 8];
#pragma unroll
        for (int n = 0; n < 4; ++n)
            w4[n] = *(const v8h*)&Wlds[pb][(quad * 128 + wo * 64 + n * 16 + l16) * 8];
#pragma unroll
        for (int m = 0; m < 8; ++m)
#pragma unroll
            for (int n = 0; n < 4; ++n)
                acc[m][n] = __builtin_amdgcn_mfma_f32_16x16x32_f16(
                    a[m], w4[n], acc[m][n], 0, 0, 0);
    };

    // prologue: stage 2 K-steps ahead
    stage(0, 0);
    stage(1, 1);
    int pb = 0, sb = 2;
#pragma unroll 3
    for (int k = 0; k < nIter; ++k) {
        __syncthreads();
        if (k + 2 < nIter)      { stage(k + 2, sb); wait_vm12(); }
        else if (k + 1 < nIter) { wait_vm6(); }
        else                    { wait_vm0(); }
        __syncthreads();
        compute(pb);
        pb = (pb == 2) ? 0 : pb + 1;
        sb = (sb == 2) ? 0 : sb + 1;
    }

    // epilogue: bias + activation + (store | pool) + per-o sum/sumsq
    float Sl[4] = {0, 0, 0, 0}, Ql[4] = {0, 0, 0, 0};
#pragma unroll
    for (int n = 0; n < 4; ++n) {
        const int o  = oB + wo * 64 + n * 16 + l16;
        const float bs = bias[o];
        f16* orow = nullptr;
        if constexpr (!POOL)
            orow = outT + (size_t)b * O * TS + (size_t)(o >> 3) * TS * 8 + (o & 7);
#pragma unroll
        for (int m = 0; m < 8; ++m)
#pragma unroll
            for (int r = 0; r < 4; ++r) {
                const int t = tB + wt * 128 + m * 16 + quad * 4 + r;
                if (t < Tout) {
                    float v = acc[m][n][r] + bs;
                    v = fmaxf(v, 0.f);
                    if (ACT == 2) v = fminf(v, 6.f);
                    if constexpr (!POOL) orow[(size_t)t * 8] = (f16)v;
                    Sl[n] += v; Ql[n] += v * v;
                }
            }
    }
#pragma unroll
    for (int n = 0; n < 4; ++n) {
        float s = Sl[n], q = Ql[n];
        s += __shfl_down(s, 32); q += __shfl_down(q, 32);
        s += __shfl_down(s, 16); q += __shfl_down(q, 16);
        if (lane < 16) { redS[wave][n * 16 + lane] = s; redQ[wave][n * 16 + lane] = q; }
    }
    __syncthreads();
    if (tid < 128) {
        const int wo2 = tid >> 6;                        // o-half
        const float s = redS[wo2 * 2][tid & 63] + redS[wo2 * 2 + 1][tid & 63];
        const float q = redQ[wo2 * 2][tid & 63] + redQ[wo2 * 2 + 1][tid & 63];
        if constexpr (POOL) {
            Sp[((size_t)blockIdx.x * B + b) * Opad + oB + tid] = s;
            Qp[((size_t)blockIdx.x * B + b) * Opad + oB + tid] = q;
        } else {
            atomicAdd(&st[oB + tid], s);
            atomicAdd(&st[512 + oB + tid], q);
        }
    }
}

// bn5 (global over B,T) + per-(b,c) mean/std(ddof=1) -> stat [B, 2*Oreal]
__global__ __launch_bounds__(256) void pool_finalize(
    const float* __restrict__ Sp, const float* __restrict__ Qp,
    const float* __restrict__ g5, const float* __restrict__ b5,
    float* __restrict__ stat, int Opad, int Oreal, int T)
{
    int co = blockIdx.x * 256 + threadIdx.x;
    if (co >= Oreal) return;
    double sS = 0, sQ = 0;
    for (int z = 0; z < 8; ++z)
        for (int b = 0; b < B; ++b) {
            sS += Sp[((size_t)z * B + b) * Opad + co];
            sQ += Qp[((size_t)z * B + b) * Opad + co];
        }
    double invN = 1.0 / ((double)B * T);
    double m = sS * invN;
    double v = sQ * invN - m * m;
    float sc = g5[co] * rsqrtf((float)v + EPSF);
    float sh = b5[co] - (float)m * sc;
    for (int b = 0; b < B; ++b) {
        double sb = 0, qb = 0;
        for (int z = 0; z < 8; ++z) {
            sb += Sp[((size_t)z * B + b) * Opad + co];
            qb += Qp[((size_t)z * B + b) * Opad + co];
        }
        double mb = sb / T;
        double vb = (qb - sb * sb / T) / (T - 1);
        if (vb < 0) vb = 0;
        stat[(size_t)b * 2 * Oreal + co]         = (float)mb * sc + sh;
        stat[(size_t)b * 2 * Oreal + Oreal + co] = sqrtf((float)vb) * fabsf(sc);
    }
}

// wave-per-output FC: y[b,o] = relu6( dot(x[b,:], W[o,:]) + bias[o] )
__global__ __launch_bounds__(256) void fc_relu6(const float* __restrict__ x,
                                                const float* __restrict__ W,
                                                const float* __restrict__ bias,
                                                float* __restrict__ y, int Cin, int O)
{
    int wid = (blockIdx.x * 256 + threadIdx.x) >> 6;
    int lane = threadIdx.x & 63;
    if (wid >= B * O) return;
    int b = wid / O, o = wid - b * O;
    const float* xr = x + (size_t)b * Cin;
    const float* wr = W + (size_t)o * Cin;
    float s = 0.f;
    for (int c = lane; c < Cin; c += 64) s = fmaf(xr[c], wr[c], s);
#pragma unroll
    for (int d = 32; d; d >>= 1) s += __shfl_down(s, d);
    if (lane == 0) y[wid] = fminf(fmaxf(s + bias[o], 0.f), 6.f);
}

// BatchNorm over batch dim on [B, O]
__global__ __launch_bounds__(512) void bn_batch(const float* __restrict__ x,
                                                const float* __restrict__ g,
                                                const float* __restrict__ be,
                                                float* __restrict__ y, int O)
{
    int o = threadIdx.x;
    if (o >= O) return;
    float s = 0.f, q = 0.f;
    for (int b = 0; b < B; ++b) { float v = x[b * O + o]; s += v; q += v * v; }
    float m = s / B;
    float var = q / B - m * m;
    float sc = g[o] * rsqrtf(var + EPSF);
    float sh = be[o] - m * sc;
    for (int b = 0; b < B; ++b) y[b * O + o] = x[b * O + o] * sc + sh;
}

} // anonymous namespace

extern "C" void kernel_launch(void* const* d_in, const int* in_sizes, int n_in,
                              void* d_out, int out_size, void* d_ws, size_t ws_size,
                              hipStream_t stream)
{
    (void)in_sizes; (void)n_in; (void)out_size; (void)ws_size;
    const float* x     = (const float*)d_in[0];
    const float* h1_w  = (const float*)d_in[1];
    const float* h1_b  = (const float*)d_in[2];
    const float* h2_w  = (const float*)d_in[3];
    const float* h2_b  = (const float*)d_in[4];
    const float* bn2_g = (const float*)d_in[5];
    const float* bn2_b = (const float*)d_in[6];
    const float* h3_w  = (const float*)d_in[7];
    const float* h3_b  = (const float*)d_in[8];
    const float* bn3_g = (const float*)d_in[9];
    const float* bn3_b = (const float*)d_in[10];
    const float* h4_w  = (const float*)d_in[11];
    const float* h4_b  = (const float*)d_in[12];
    const float* bn4_g = (const float*)d_in[13];
    const float* bn4_b = (const float*)d_in[14];
    const float* h5_w  = (const float*)d_in[15];
    const float* h5_b  = (const float*)d_in[16];
    const float* bn5_g = (const float*)d_in[17];
    const float* bn5_b = (const float*)d_in[18];
    const float* l1_w  = (const float*)d_in[19];
    const float* l1_b  = (const float*)d_in[20];
    const float* bn6_g = (const float*)d_in[21];
    const float* bn6_b = (const float*)d_in[22];
    const float* l2_w  = (const float*)d_in[23];
    const float* l2_b  = (const float*)d_in[24];
    const float* bn7_g = (const float*)d_in[25];
    const float* bn7_b = (const float*)d_in[26];

    char* ws = (char*)d_ws;
    size_t off = 0;
    auto alloc = [&](size_t bytes) {
        char* p = ws + off;
        off += (bytes + 255) & ~(size_t)255;
        return (void*)p;
    };
    f16* xT    = (f16*)alloc(((size_t)B * 3  * TS * 8 + 2048) * 2);
    f16* bufA  = (f16*)alloc(((size_t)B * 64 * TS * 8 + 2048) * 2);  // o1, later o3
    f16* bufB  = (f16*)alloc(((size_t)B * 64 * TS * 8 + 2048) * 2);  // o2, later o4
    f16* Wh1   = (f16*)alloc((size_t)512 * 128 * 2);
    f16* Wh2   = (f16*)alloc((size_t)512 * 1536 * 2);
    f16* Wh3   = (f16*)alloc((size_t)512 * 1536 * 2);
    f16* Wh4   = (f16*)alloc((size_t)512 * 512 * 2);
    f16* Wh5   = (f16*)alloc((size_t)1536 * 512 * 2);
    float* bf1 = (float*)alloc(512 * 4);
    float* bf2 = (float*)alloc(512 * 4);
    float* bf3 = (float*)alloc(512 * 4);
    float* bf4 = (float*)alloc(512 * 4);
    float* bf5 = (float*)alloc(1536 * 4);
    float* stZ = (float*)alloc(4096 * 4);       // st1..st4, zeroed by transpose_x
    float* st1 = stZ, *st2 = stZ + 1024, *st3 = stZ + 2048, *st4 = stZ + 3072;
    float* Sp  = (float*)alloc((size_t)8 * B * 1536 * 4);
    float* Qp  = (float*)alloc((size_t)8 * B * 1536 * 4);
    float* stat = (float*)alloc((size_t)B * 3000 * 4);
    float* f1  = (float*)alloc((size_t)B * 512 * 4);
    float* f2  = (float*)alloc((size_t)B * 512 * 4);

    transpose_x<<<(B * 3 * TS * 8 + 255) / 256, 256, 0, stream>>>(x, xT, stZ);

    // L1: reorder/cast/swizzle W1 (no prev BN); splice(0..4), Cin pad->128
    fold_mfma<24, 5><<<512, 256, 0, stream>>>(h1_w, h1_b, nullptr, nullptr, nullptr,
                                              Wh1, bf1, 512, 20, 128, 100, 0.f);
    conv_mfma<1, 24, 128><<<dim3(16, 4, B), 256, 0, stream>>>(
        xT, Wh1, bf1, bufA, st1, 512, T1, 1);

    // L2: fold bn1 (no affine); splice(0,2,4) -> deep-prefetch kernel
    fold_mfma<512, 3><<<512, 256, 0, stream>>>(h2_w, h2_b, st1, nullptr, nullptr,
                                               Wh2, bf2, 512, 512, 1536, 1536,
                                               1.f / (B * T1));
    conv2b<1, 1536, false><<<dim3(8, 4, B), 256, 0, stream>>>(
        bufA, Wh2, bf2, bufB, st2, nullptr, nullptr, 512, T2, 2, 0);

    // L3: fold bn2; splice(0,3,6)
    fold_mfma<512, 3><<<512, 256, 0, stream>>>(h3_w, h3_b, st2, bn2_g, bn2_b,
                                               Wh3, bf3, 512, 512, 1536, 1536,
                                               1.f / (B * T2));
    conv2b<1, 1536, false><<<dim3(8, 4, B), 256, 0, stream>>>(
        bufB, Wh3, bf3, bufA, st3, nullptr, nullptr, 512, T3, 3, 0);

    // L4: fold bn3; conv 512x512, relu6
    fold_mfma<512, 1><<<512, 256, 0, stream>>>(h4_w, h4_b, st3, bn3_g, bn3_b,
                                               Wh4, bf4, 512, 512, 512, 512,
                                               1.f / (B * T3));
    conv2b<2, 512, false><<<dim3(8, 4, B), 256, 0, stream>>>(
        bufA, Wh4, bf4, bufB, st4, nullptr, nullptr, 512, T3, 0, 0);

    // L5: fold bn4; conv 1500(pad 1536)x512 + relu6 + fused 256-t-zone reduction
    fold_mfma<512, 1><<<1536, 256, 0, stream>>>(h5_w, h5_b, st4, bn4_g, bn4_b,
                                                Wh5, bf5, 1500, 512, 512, 512,
                                                1.f / (B * T3));
    conv2b<2, 512, true><<<dim3(8, 12, B), 256, 0, stream>>>(
        bufB, Wh5, bf5, nullptr, nullptr, Sp, Qp, 1536, T3, 0, 1536);

    // bn5 + stats pooling -> stat [B,3000]
    pool_finalize<<<6, 256, 0, stream>>>(Sp, Qp, bn5_g, bn5_b, stat, 1536, 1500, T3);

    // FC head
    fc_relu6<<<(B * 512 * 64 + 255) / 256, 256, 0, stream>>>(stat, l1_w, l1_b, f1, 3000, 512);
    bn_batch<<<1, 512, 0, stream>>>(f1, bn6_g, bn6_b, f1, 512);
    fc_relu6<<<(B * 512 * 64 + 255) / 256, 256, 0, stream>>>(f1, l2_w, l2_b, f2, 512, 512);
    bn_batch<<<1, 512, 0, stream>>>(f2, bn7_g, bn7_b, (float*)d_out, 512);
}